// Round 1
// baseline (2320.915 us; speedup 1.0000x reference)
//
#include <hip/hip_runtime.h>
#include <hip/hip_bf16.h>

#define N_NODES 327680
#define N_EDGES 2621440
#define NGRAPH  8192

__global__ void k_deg_init(float* deg){
    int i = blockIdx.x*256 + threadIdx.x;
    if (i < N_NODES) deg[i] = 1.0f;            // self-loop
}

__global__ void k_deg_edges(const int* __restrict__ dst, float* deg){
    int e = blockIdx.x*256 + threadIdx.x;
    if (e < N_EDGES) atomicAdd(&deg[dst[e]], 1.0f);
}

__global__ void k_dinv(const float* __restrict__ deg, float* dinv){
    int i = blockIdx.x*256 + threadIdx.x;
    if (i < N_NODES) dinv[i] = 1.0f / sqrtf(deg[i]);
}

// out[i][:] = feat[i][:] * dinv[i]^2   (self-loop term), wave per node
template<int D>
__global__ void k_selfloop(const float* __restrict__ feat, const float* __restrict__ dinv,
                           float* __restrict__ out){
    int idx  = blockIdx.x*256 + threadIdx.x;
    int i    = idx >> 6;
    int lane = idx & 63;
    if (i < N_NODES && lane < D){
        float dv = dinv[i];
        out[(size_t)i*D + lane] = feat[(size_t)i*D + lane] * dv * dv;
    }
}

// wave per edge: out[dst][:] += feat[src][:] * dinv[src]*dinv[dst]
template<int D>
__global__ void k_edge_agg(const int* __restrict__ src, const int* __restrict__ dst,
                           const float* __restrict__ dinv, const float* __restrict__ feat,
                           float* __restrict__ out){
    int idx  = blockIdx.x*256 + threadIdx.x;
    int e    = idx >> 6;          // wave-uniform
    int lane = idx & 63;
    if (e >= N_EDGES) return;
    int s = src[e], d = dst[e];
    float nrm = dinv[s] * dinv[d];
    if (lane < D)
        atomicAdd(&out[(size_t)d*D + lane], feat[(size_t)s*D + lane] * nrm);
}

// per-row fused: t = relu(agg1 @ W1 + b1) @ W2
// block = 256 threads, 2 rows at a time (128 threads each), 8 iterations
__global__ __launch_bounds__(256) void k_fused_w1w2(
        const float* __restrict__ agg1, const float* __restrict__ W1,
        const float* __restrict__ b1,   const float* __restrict__ W2,
        float* __restrict__ tout){
    __shared__ float sW1[58*96];
    __shared__ float sW2[96*48];
    __shared__ float srow[2][58];
    __shared__ float sh1[2][96];
    for (int t = threadIdx.x; t < 58*96; t += 256) sW1[t] = W1[t];
    for (int t = threadIdx.x; t < 96*48; t += 256) sW2[t] = W2[t];
    int half = threadIdx.x >> 7;     // 0/1
    int tid  = threadIdx.x & 127;
    int base = blockIdx.x * 16;
    for (int it = 0; it < 8; ++it){
        int row = base + it*2 + half;
        __syncthreads();                      // weights ready / srow,sh1 safe to reuse
        if (tid < 58) srow[half][tid] = agg1[(size_t)row*58 + tid];
        __syncthreads();
        if (tid < 96){
            float acc = b1[tid];
            #pragma unroll
            for (int k = 0; k < 58; ++k) acc += srow[half][k] * sW1[k*96 + tid];
            sh1[half][tid] = fmaxf(acc, 0.f);
        }
        __syncthreads();
        if (tid < 48){
            float acc = 0.f;
            #pragma unroll
            for (int k = 0; k < 96; ++k) acc += sh1[half][k] * sW2[k*48 + tid];
            tout[(size_t)row*48 + tid] = acc;
        }
    }
}

__global__ void k_bias_relu48(float* __restrict__ h, const float* __restrict__ b2){
    int idx = blockIdx.x*256 + threadIdx.x;
    if (idx < N_NODES*48){
        int c = idx % 48;
        h[idx] = fmaxf(h[idx] + b2[c], 0.f);
    }
}

// C[M,N] = relu?(A[M,K] @ B[K,N] + bias);  M,N multiples of 64, K multiple of 16
template<int RELU>
__global__ __launch_bounds__(256) void k_gemm(
        const float* __restrict__ A, const float* __restrict__ B,
        const float* __restrict__ bias, float* __restrict__ C,
        int M, int Nn, int K){
    __shared__ float As[64][17];
    __shared__ float Bs[16][65];
    int tx = threadIdx.x & 15, ty = threadIdx.x >> 4;
    int row0 = blockIdx.y * 64, col0 = blockIdx.x * 64;
    float acc[4][4] = {};
    for (int k0 = 0; k0 < K; k0 += 16){
        for (int t = threadIdx.x; t < 64*16; t += 256){
            int r = t >> 4, c = t & 15;
            As[r][c] = A[(size_t)(row0 + r)*K + k0 + c];
        }
        for (int t = threadIdx.x; t < 16*64; t += 256){
            int r = t >> 6, c = t & 63;
            Bs[r][c] = B[(size_t)(k0 + r)*Nn + col0 + c];
        }
        __syncthreads();
        #pragma unroll
        for (int k = 0; k < 16; ++k){
            float a[4], b[4];
            #pragma unroll
            for (int i = 0; i < 4; ++i) a[i] = As[ty*4 + i][k];
            #pragma unroll
            for (int j = 0; j < 4; ++j) b[j] = Bs[k][tx*4 + j];
            #pragma unroll
            for (int i = 0; i < 4; ++i)
                #pragma unroll
                for (int j = 0; j < 4; ++j) acc[i][j] += a[i] * b[j];
        }
        __syncthreads();
    }
    #pragma unroll
    for (int i = 0; i < 4; ++i){
        int r = row0 + ty*4 + i;
        #pragma unroll
        for (int j = 0; j < 4; ++j){
            int c = col0 + tx*4 + j;
            float v = acc[i][j] + bias[c];
            if (RELU) v = fmaxf(v, 0.f);
            C[(size_t)r*Nn + c] = v;
        }
    }
}

// out[row] = sigmoid(dot(g2[row,:64], w3) + b3), wave per row
__global__ void k_final(const float* __restrict__ g2, const float* __restrict__ w3,
                        const float* __restrict__ b3, float* __restrict__ out){
    int idx  = blockIdx.x*256 + threadIdx.x;
    int row  = idx >> 6;
    int lane = idx & 63;
    if (row >= NGRAPH) return;
    float v = g2[(size_t)row*64 + lane] * w3[lane];
    #pragma unroll
    for (int o = 32; o > 0; o >>= 1) v += __shfl_xor(v, o);
    if (lane == 0) out[row] = 1.0f / (1.0f + expf(-(v + b3[0])));
}

extern "C" void kernel_launch(void* const* d_in, const int* in_sizes, int n_in,
                              void* d_out, int out_size, void* d_ws, size_t ws_size,
                              hipStream_t stream){
    const float* x   = (const float*)d_in[0];
    const int*   ei  = (const int*)  d_in[1];
    const int*   src = ei;
    const int*   dst = ei + N_EDGES;
    const float* W1  = (const float*)d_in[2];
    const float* b1  = (const float*)d_in[3];
    const float* W2  = (const float*)d_in[4];
    const float* b2  = (const float*)d_in[5];
    const float* l1w = (const float*)d_in[6];
    const float* l1b = (const float*)d_in[7];
    const float* l2w = (const float*)d_in[8];
    const float* l2b = (const float*)d_in[9];
    const float* l3w = (const float*)d_in[10];
    const float* l3b = (const float*)d_in[11];
    float* out = (float*)d_out;

    float* ws   = (float*)d_ws;
    float* dinv = ws;                                  // N
    float* agg1 = dinv + N_NODES;                      // N*58  (reused as agg2)
    float* tbuf = agg1 + (size_t)N_NODES*58;           // N*48
    float* g1   = tbuf + (size_t)N_NODES*48;           // 8192*256
    float* g2   = g1 + (size_t)NGRAPH*256;             // 8192*64
    float* deg  = g1;                                  // reuse (only needed early)
    float* agg2 = agg1;                                // reuse (agg1 dead after fused)

    k_deg_init  <<<(N_NODES+255)/256, 256, 0, stream>>>(deg);
    k_deg_edges <<<(N_EDGES+255)/256, 256, 0, stream>>>(dst, deg);
    k_dinv      <<<(N_NODES+255)/256, 256, 0, stream>>>(deg, dinv);

    // conv1: aggregate x (58 dims), then fused (W1 -> relu -> W2) per row
    k_selfloop<58> <<<N_NODES/4, 256, 0, stream>>>(x, dinv, agg1);
    k_edge_agg<58> <<<N_EDGES/4, 256, 0, stream>>>(src, dst, dinv, x, agg1);
    k_fused_w1w2   <<<N_NODES/16, 256, 0, stream>>>(agg1, W1, b1, W2, tbuf);

    // conv2: aggregate t (48 dims), then bias+relu
    k_selfloop<48> <<<N_NODES/4, 256, 0, stream>>>(tbuf, dinv, agg2);
    k_edge_agg<48> <<<N_EDGES/4, 256, 0, stream>>>(src, dst, dinv, tbuf, agg2);
    k_bias_relu48  <<<(N_NODES*48+255)/256, 256, 0, stream>>>(agg2, b2);

    // MLP head: [8192,1920] -> 256 -> 64 -> 1(sigmoid)
    k_gemm<1> <<<dim3(256/64, NGRAPH/64), 256, 0, stream>>>(agg2, l1w, l1b, g1, NGRAPH, 256, 1920);
    k_gemm<1> <<<dim3(64/64,  NGRAPH/64), 256, 0, stream>>>(g1,   l2w, l2b, g2, NGRAPH, 64, 256);
    k_final   <<<NGRAPH/4, 256, 0, stream>>>(g2, l3w, l3b, out);
}

// Round 2
// 1025.994 us; speedup vs baseline: 2.2621x; 2.2621x over previous
//
#include <hip/hip_runtime.h>

#define N_NODES 327680
#define N_EDGES 2621440
#define NGRAPH  8192

typedef unsigned int uint;
typedef unsigned short u16;

__device__ __forceinline__ float b2f(u16 h){ return __uint_as_float(((uint)h)<<16); }
__device__ __forceinline__ u16 f2b(float f){
    uint u = __float_as_uint(f);
    u += 0x7fffu + ((u>>16)&1u);          // round-to-nearest-even
    return (u16)(u>>16);
}

// ---------------- degree / CSR build ----------------

__global__ void k_zero(int* __restrict__ p, int n){
    int i = blockIdx.x*256 + threadIdx.x;
    if (i < n) p[i] = 0;
}

__global__ void k_hist(const int* __restrict__ dst, int* __restrict__ deg){
    int e = blockIdx.x*256 + threadIdx.x;
    if (e < N_EDGES) atomicAdd(&deg[dst[e]], 1);
}

__global__ void k_dinv(const int* __restrict__ deg, float* __restrict__ dinv){
    int i = blockIdx.x*256 + threadIdx.x;
    if (i < N_NODES) dinv[i] = 1.0f / sqrtf((float)(deg[i] + 1));  // +1 self-loop
}

// exclusive scan of N_NODES ints, in place. 320 blocks x 1024 elems.
__global__ __launch_bounds__(256) void k_scan1(int* __restrict__ data, int* __restrict__ bsum){
    __shared__ int ts[256];
    int base = blockIdx.x*1024 + threadIdx.x*4;
    int4 v = *(const int4*)&data[base];
    int s = v.x + v.y + v.z + v.w;
    ts[threadIdx.x] = s;
    __syncthreads();
    for (int o = 1; o < 256; o <<= 1){
        int t = (threadIdx.x >= o) ? ts[threadIdx.x - o] : 0;
        __syncthreads();
        ts[threadIdx.x] += t;
        __syncthreads();
    }
    int excl = threadIdx.x ? ts[threadIdx.x-1] : 0;
    int4 w;
    w.x = excl; w.y = w.x + v.x; w.z = w.y + v.y; w.w = w.z + v.z;
    *(int4*)&data[base] = w;
    if (threadIdx.x == 255) bsum[blockIdx.x] = ts[255];
}

__global__ __launch_bounds__(512) void k_scan2(const int* __restrict__ bsum, int* __restrict__ bofs){
    __shared__ int ts[512];
    int v = (threadIdx.x < 320) ? bsum[threadIdx.x] : 0;
    ts[threadIdx.x] = v;
    __syncthreads();
    for (int o = 1; o < 512; o <<= 1){
        int t = (threadIdx.x >= o) ? ts[threadIdx.x - o] : 0;
        __syncthreads();
        ts[threadIdx.x] += t;
        __syncthreads();
    }
    if (threadIdx.x < 320) bofs[threadIdx.x] = ts[threadIdx.x] - v;  // exclusive
}

__global__ void k_scan3(int* __restrict__ rs, const int* __restrict__ bofs, int* __restrict__ cursor){
    int i = blockIdx.x*256 + threadIdx.x;
    if (i < N_NODES){
        int v = rs[i] + bofs[i>>10];
        rs[i] = v;
        cursor[i] = v;
    }
}

__global__ void k_scatter(const int* __restrict__ src, const int* __restrict__ dst,
                          int* __restrict__ cursor, int* __restrict__ csr_src){
    int e = blockIdx.x*256 + threadIdx.x;
    if (e < N_EDGES){
        int d = dst[e];
        int pos = atomicAdd(&cursor[d], 1);
        csr_src[pos] = src[e];
    }
}

// ---------------- feature prescale (feat * dinv[row] -> bf16) ----------------

template<int D>
__global__ void k_prescale_f32(const float* __restrict__ feat, const float* __restrict__ dinv,
                               u16* __restrict__ out){
    int idx = blockIdx.x*256 + threadIdx.x;
    int r = idx / D;
    out[idx] = f2b(feat[idx] * dinv[r]);
}

template<int D>
__global__ void k_prescale_b16(const u16* __restrict__ feat, const float* __restrict__ dinv,
                               u16* __restrict__ out){
    int idx = blockIdx.x*256 + threadIdx.x;
    int r = idx / D;
    out[idx] = f2b(b2f(feat[idx]) * dinv[r]);
}

// ---------------- CSR gather: out[i] = dinv[i]*(featsc[i] + sum featsc[src]) ----------------

template<int D, int BIASRELU>
__global__ void k_gather(const int* __restrict__ rs, const int* __restrict__ rend,
                         const int* __restrict__ csr_src, const float* __restrict__ dinv,
                         const u16* __restrict__ feat, const float* __restrict__ bias,
                         u16* __restrict__ out){
    int gid  = blockIdx.x*256 + threadIdx.x;
    int node = gid >> 6;
    int lane = gid & 63;
    float di  = dinv[node];
    float acc = 0.f;
    if (lane < D) acc = b2f(feat[(size_t)node*D + lane]);   // self term (featsc includes dinv[i])
    int e  = rs[node];
    int e1 = rend[node];
    for (; e + 1 < e1; e += 2){
        int s0 = csr_src[e];
        int s1 = csr_src[e+1];
        if (lane < D){
            acc += b2f(feat[(size_t)s0*D + lane]);
            acc += b2f(feat[(size_t)s1*D + lane]);
        }
    }
    if (e < e1){
        int s0 = csr_src[e];
        if (lane < D) acc += b2f(feat[(size_t)s0*D + lane]);
    }
    if (lane < D){
        float v = acc * di;
        if (BIASRELU) v = fmaxf(v + bias[lane], 0.f);
        out[(size_t)node*D + lane] = f2b(v);
    }
}

// ---------------- node-feature GEMM: C[64rows x NOUT] = act(A @ W + b) ----------------
// A bf16 [rows x K], W f32 [K x NOUT] fully in LDS, A tile transposed in LDS.

template<int K, int NOUT, int BIAS, int RELU>
__global__ __launch_bounds__(256) void k_gemm_node(
        const u16* __restrict__ A, const float* __restrict__ W,
        const float* __restrict__ bias, u16* __restrict__ C){
    constexpr int CPT   = NOUT/16;   // cols per thread
    constexpr int PAIRS = K/2;
    __shared__ float As[K][68];
    __shared__ float sW[K*NOUT];
    __shared__ float sb[NOUT];
    for (int t = threadIdx.x; t < K*NOUT; t += 256) sW[t] = W[t];
    if (BIAS && threadIdx.x < NOUT) sb[threadIdx.x] = bias[threadIdx.x];
    const uint* A32 = (const uint*)(A + (size_t)blockIdx.x*64*K);
    for (int t = threadIdx.x; t < 64*PAIRS; t += 256){
        int r = t / PAIRS, c = t % PAIRS;
        uint u = A32[r*PAIRS + c];
        As[2*c  ][r] = __uint_as_float(u << 16);
        As[2*c+1][r] = __uint_as_float(u & 0xffff0000u);
    }
    __syncthreads();
    int tx = threadIdx.x & 15, ty = threadIdx.x >> 4;
    float acc[4][CPT] = {};
    for (int k = 0; k < K; ++k){
        float4 a = *(const float4*)&As[k][ty*4];
        const float* ap = (const float*)&a;
        float wv[CPT];
        #pragma unroll
        for (int j = 0; j < CPT; ++j) wv[j] = sW[k*NOUT + tx*CPT + j];
        #pragma unroll
        for (int i = 0; i < 4; ++i)
            #pragma unroll
            for (int j = 0; j < CPT; ++j) acc[i][j] += ap[i] * wv[j];
    }
    size_t row0 = (size_t)blockIdx.x*64;
    #pragma unroll
    for (int i = 0; i < 4; ++i){
        size_t r = row0 + ty*4 + i;
        #pragma unroll
        for (int j = 0; j < CPT; ++j){
            float v = acc[i][j] + (BIAS ? sb[tx*CPT + j] : 0.f);
            if (RELU) v = fmaxf(v, 0.f);
            C[r*NOUT + tx*CPT + j] = f2b(v);
        }
    }
}

// ---------------- MLP GEMM: 64x64 tile, A bf16, B f32 ----------------

template<int RELU>
__global__ __launch_bounds__(256) void k_gemm_mlp(
        const u16* __restrict__ A, const float* __restrict__ B,
        const float* __restrict__ bias, u16* __restrict__ C,
        int Nn, int K){
    __shared__ float As[16][68];
    __shared__ float Bs[16][68];
    int row0 = blockIdx.y*64, col0 = blockIdx.x*64;
    int tx = threadIdx.x & 15, ty = threadIdx.x >> 4;
    float acc[4][4] = {};
    for (int k0 = 0; k0 < K; k0 += 16){
        #pragma unroll
        for (int it = 0; it < 2; ++it){
            int t = threadIdx.x + it*256;
            int r = t >> 3, c = t & 7;
            uint u = *(const uint*)(A + (size_t)(row0 + r)*K + k0 + 2*c);
            As[2*c  ][r] = __uint_as_float(u << 16);
            As[2*c+1][r] = __uint_as_float(u & 0xffff0000u);
        }
        #pragma unroll
        for (int it = 0; it < 4; ++it){
            int t = threadIdx.x + it*256;
            int r = t >> 6, c = t & 63;
            Bs[r][c] = B[(size_t)(k0 + r)*Nn + col0 + c];
        }
        __syncthreads();
        #pragma unroll
        for (int k = 0; k < 16; ++k){
            float4 a = *(const float4*)&As[k][ty*4];
            float4 b = *(const float4*)&Bs[k][tx*4];
            const float* ap = (const float*)&a;
            const float* bp = (const float*)&b;
            #pragma unroll
            for (int i = 0; i < 4; ++i)
                #pragma unroll
                for (int j = 0; j < 4; ++j) acc[i][j] += ap[i]*bp[j];
        }
        __syncthreads();
    }
    #pragma unroll
    for (int i = 0; i < 4; ++i){
        size_t r = row0 + ty*4 + i;
        #pragma unroll
        for (int j = 0; j < 4; ++j){
            float v = acc[i][j] + bias[col0 + tx*4 + j];
            if (RELU) v = fmaxf(v, 0.f);
            C[r*Nn + col0 + tx*4 + j] = f2b(v);
        }
    }
}

// ---------------- final: sigmoid(g2 @ w3 + b3) ----------------

__global__ void k_final(const u16* __restrict__ g2, const float* __restrict__ w3,
                        const float* __restrict__ b3, float* __restrict__ out){
    int gid  = blockIdx.x*256 + threadIdx.x;
    int row  = gid >> 6;
    int lane = gid & 63;
    float v = b2f(g2[(size_t)row*64 + lane]) * w3[lane];
    #pragma unroll
    for (int o = 32; o; o >>= 1) v += __shfl_xor(v, o);
    if (!lane) out[row] = 1.0f / (1.0f + expf(-(v + b3[0])));
}

extern "C" void kernel_launch(void* const* d_in, const int* in_sizes, int n_in,
                              void* d_out, int out_size, void* d_ws, size_t ws_size,
                              hipStream_t stream){
    const float* x   = (const float*)d_in[0];
    const int*   ei  = (const int*)  d_in[1];
    const int*   src = ei;
    const int*   dst = ei + N_EDGES;
    const float* W1  = (const float*)d_in[2];
    const float* b1  = (const float*)d_in[3];
    const float* W2  = (const float*)d_in[4];
    const float* b2  = (const float*)d_in[5];
    const float* l1w = (const float*)d_in[6];
    const float* l1b = (const float*)d_in[7];
    const float* l2w = (const float*)d_in[8];
    const float* l2b = (const float*)d_in[9];
    const float* l3w = (const float*)d_in[10];
    const float* l3b = (const float*)d_in[11];
    float* out = (float*)d_out;

    char* w = (char*)d_ws;
    float* dinv   = (float*)w; w += (size_t)N_NODES*4;
    int*   degrow = (int*)w;   w += (size_t)N_NODES*4;   // deg -> row_start (in-place scan)
    int*   cursor = (int*)w;   w += (size_t)N_NODES*4;   // after scatter: row_end
    int*   bsum   = (int*)w;   w += 2048;
    int*   bofs   = (int*)w;   w += 2048;
    int*   csr    = (int*)w;   w += (size_t)N_EDGES*4;   // later reused for g1,g2
    u16*   R1     = (u16*)w;   w += (size_t)N_NODES*58*2; // agg1, then ts
    u16*   R2     = (u16*)w;   w += (size_t)N_NODES*96*2; // xs, then h1, then agg2
    u16*   R3     = (u16*)w;   w += (size_t)N_NODES*48*2; // t
    u16* agg1 = R1; u16* ts = R1;
    u16* xs = R2;   u16* h1 = R2; u16* agg2 = R2;
    u16* tb = R3;
    u16* g1 = (u16*)csr;
    u16* g2 = g1 + (size_t)NGRAPH*256;

    // CSR build
    k_zero   <<<1280, 256, 0, stream>>>(degrow, N_NODES);
    k_hist   <<<10240,256, 0, stream>>>(dst, degrow);
    k_dinv   <<<1280, 256, 0, stream>>>(degrow, dinv);
    k_scan1  <<<320,  256, 0, stream>>>(degrow, bsum);
    k_scan2  <<<1,    512, 0, stream>>>(bsum, bofs);
    k_scan3  <<<1280, 256, 0, stream>>>(degrow, bofs, cursor);
    k_scatter<<<10240,256, 0, stream>>>(src, dst, cursor, csr);

    // conv1: prescale x, gather (58), GEMM 58->96 (+b1, relu), GEMM 96->48
    k_prescale_f32<58><<<74240, 256, 0, stream>>>(x, dinv, xs);
    k_gather<58,0>     <<<81920, 256, 0, stream>>>(degrow, cursor, csr, dinv, xs, nullptr, agg1);
    k_gemm_node<58,96,1,1><<<5120, 256, 0, stream>>>(agg1, W1, b1, h1);
    k_gemm_node<96,48,0,0><<<5120, 256, 0, stream>>>(h1, W2, nullptr, tb);

    // conv2: prescale t, gather (48) + b2 + relu
    k_prescale_b16<48><<<61440, 256, 0, stream>>>(tb, dinv, ts);
    k_gather<48,1>     <<<81920, 256, 0, stream>>>(degrow, cursor, csr, dinv, ts, b2, agg2);

    // MLP head
    k_gemm_mlp<1><<<dim3(4,128), 256, 0, stream>>>(agg2, l1w, l1b, g1, 256, 1920);
    k_gemm_mlp<1><<<dim3(1,128), 256, 0, stream>>>(g1,   l2w, l2b, g2, 64, 256);
    k_final      <<<2048, 256, 0, stream>>>(g2, l3w, l3b, out);
}

// Round 3
// 751.501 us; speedup vs baseline: 3.0884x; 1.3653x over previous
//
#include <hip/hip_runtime.h>

#define N_NODES 327680
#define N_EDGES 2621440
#define NGRAPH  8192
#define NB      640          // dst buckets (512 nodes each)

typedef unsigned int uint;
typedef unsigned short u16;
typedef __attribute__((ext_vector_type(8))) short s16x8;
typedef __attribute__((ext_vector_type(4))) float f32x4;

__device__ __forceinline__ float b2f(u16 h){ return __uint_as_float(((uint)h)<<16); }
__device__ __forceinline__ u16 f2b(float f){
    uint u = __float_as_uint(f);
    u += 0x7fffu + ((u>>16)&1u);          // round-to-nearest-even
    return (u16)(u>>16);
}

// ---------------- degree / scan ----------------

__global__ void k_zero(int* __restrict__ p, int n){
    int i = blockIdx.x*256 + threadIdx.x;
    if (i < n) p[i] = 0;
}

__global__ void k_hist(const int* __restrict__ dst, int* __restrict__ deg){
    int e = blockIdx.x*256 + threadIdx.x;
    if (e < N_EDGES) atomicAdd(&deg[dst[e]], 1);
}

__global__ void k_dinv(const int* __restrict__ deg, float* __restrict__ dinv){
    int i = blockIdx.x*256 + threadIdx.x;
    if (i < N_NODES) dinv[i] = 1.0f / sqrtf((float)(deg[i] + 1));  // +1 self-loop
}

__global__ __launch_bounds__(256) void k_scan1(int* __restrict__ data, int* __restrict__ bsum){
    __shared__ int ts[256];
    int base = blockIdx.x*1024 + threadIdx.x*4;
    int4 v = *(const int4*)&data[base];
    int s = v.x + v.y + v.z + v.w;
    ts[threadIdx.x] = s;
    __syncthreads();
    for (int o = 1; o < 256; o <<= 1){
        int t = (threadIdx.x >= o) ? ts[threadIdx.x - o] : 0;
        __syncthreads();
        ts[threadIdx.x] += t;
        __syncthreads();
    }
    int excl = threadIdx.x ? ts[threadIdx.x-1] : 0;
    int4 w;
    w.x = excl; w.y = w.x + v.x; w.z = w.y + v.y; w.w = w.z + v.z;
    *(int4*)&data[base] = w;
    if (threadIdx.x == 255) bsum[blockIdx.x] = ts[255];
}

__global__ __launch_bounds__(512) void k_scan2(const int* __restrict__ bsum, int* __restrict__ bofs){
    __shared__ int ts[512];
    int v = (threadIdx.x < 320) ? bsum[threadIdx.x] : 0;
    ts[threadIdx.x] = v;
    __syncthreads();
    for (int o = 1; o < 512; o <<= 1){
        int t = (threadIdx.x >= o) ? ts[threadIdx.x - o] : 0;
        __syncthreads();
        ts[threadIdx.x] += t;
        __syncthreads();
    }
    if (threadIdx.x < 320) bofs[threadIdx.x] = ts[threadIdx.x] - v;  // exclusive
}

__global__ void k_scan3(int* __restrict__ rs, const int* __restrict__ bofs, int* __restrict__ cursor){
    int i = blockIdx.x*256 + threadIdx.x;
    if (i < N_NODES){
        int v = rs[i] + bofs[i>>10];
        rs[i] = v;
        cursor[i] = v;
    }
}

// ---------------- bucketed CSR build ----------------

__global__ void k_gcur(const int* __restrict__ rowst, int* __restrict__ gcur){
    int i = blockIdx.x*256 + threadIdx.x;
    if (i < NB) gcur[i] = rowst[(size_t)i*512];
}

// pass A: bin edges into 640 dst-buckets (bucket regions == csr segments)
__global__ __launch_bounds__(256) void k_partition(
    const int* __restrict__ src, const int* __restrict__ dst,
    int* __restrict__ gcur, uint2* __restrict__ staging)
{
    __shared__ int cnt[NB], base_[NB];
    int tid = threadIdx.x;
    for (int i = tid; i < NB; i += 256) cnt[i] = 0;
    __syncthreads();
    int e0 = blockIdx.x*4096;
    int d[16];
    #pragma unroll
    for (int j = 0; j < 16; ++j){
        d[j] = dst[e0 + j*256 + tid];
        atomicAdd(&cnt[d[j] >> 9], 1);
    }
    __syncthreads();
    for (int i = tid; i < NB; i += 256)
        base_[i] = atomicAdd(&gcur[i], cnt[i]);
    __syncthreads();
    for (int i = tid; i < NB; i += 256) cnt[i] = 0;
    __syncthreads();
    #pragma unroll
    for (int j = 0; j < 16; ++j){
        int e = e0 + j*256 + tid;
        int b = d[j] >> 9;
        int r = atomicAdd(&cnt[b], 1);
        staging[base_[b] + r] = make_uint2((uint)src[e], (uint)d[j]);
    }
}

// pass B: one block per bucket; all atomics/writes confined to a small window
__global__ __launch_bounds__(256) void k_finalize(
    const uint2* __restrict__ staging, const int* __restrict__ rowst,
    int* __restrict__ cursor, int* __restrict__ csr)
{
    int b = blockIdx.x;
    int lo = rowst[b*512];
    int hi = (b == NB-1) ? N_EDGES : rowst[(b+1)*512];
    for (int t = lo + (int)threadIdx.x; t < hi; t += 256){
        uint2 e = staging[t];
        int pos = atomicAdd(&cursor[e.y], 1);
        csr[pos] = (int)e.x;
    }
}

// ---------------- weight convert ----------------

__global__ void k_f2bf(const float* __restrict__ in, u16* __restrict__ out, int n){
    int i = blockIdx.x*256 + threadIdx.x;
    if (i < n) out[i] = f2b(in[i]);
}

// ---------------- prescale x*dinv -> bf16, padded to 64 cols ----------------

__global__ void k_prescale(const float* __restrict__ x, const float* __restrict__ dinv,
                           u16* __restrict__ xs){
    int gid = blockIdx.x*256 + threadIdx.x;
    int r = gid >> 6, lane = gid & 63;
    float v = (lane < 58) ? x[(size_t)r*58 + lane] * dinv[r] : 0.f;
    xs[(size_t)r*64 + lane] = f2b(v);
}

// ---------------- CSR gather: out[i] = act(dinv[i]*(feat[i] + sum feat[src])) ----------------
// feat rows padded to 64 (128B aligned)

template<int OUTW, int BR>
__global__ void k_gather(const int* __restrict__ rs, const int* __restrict__ rend,
                         const int* __restrict__ csr, const float* __restrict__ dinv,
                         const u16* __restrict__ feat, const float* __restrict__ bias,
                         u16* __restrict__ out)
{
    int gid = blockIdx.x*256 + threadIdx.x;
    int node = gid >> 6, lane = gid & 63;
    float di = dinv[node];
    float acc = b2f(feat[(size_t)node*64 + lane]);
    int e = rs[node], e1 = rend[node];
    for (; e + 1 < e1; e += 2){
        int s0 = csr[e], s1 = csr[e+1];
        acc += b2f(feat[(size_t)s0*64 + lane]);
        acc += b2f(feat[(size_t)s1*64 + lane]);
    }
    if (e < e1) acc += b2f(feat[(size_t)csr[e]*64 + lane]);
    float v = acc * di;
    if (BR){
        if (lane < 48)
            out[(size_t)node*48 + lane] = f2b(fmaxf(v + bias[lane], 0.f));
    } else {
        out[(size_t)node*OUTW + lane] = f2b(v);
    }
}

// ---------------- fused conv MLP: ts = (relu(agg1 @ W1 + b1) @ W2) * dinv  (MFMA) ----------------

__global__ __launch_bounds__(256) void k_conv_mlp(
    const u16* __restrict__ A,      // agg1 [N][64] (58 real cols, rest 0)
    const u16* __restrict__ w1,     // [58][96] bf16
    const float* __restrict__ b1,   // [96]
    const u16* __restrict__ w2,     // [96][48] bf16
    const float* __restrict__ dinv,
    u16* __restrict__ ts)           // [N][64], cols>=48 zeroed here
{
    __shared__ __align__(16) u16 As[64][72];
    __shared__ __align__(16) u16 Bt1[96][72];
    __shared__ __align__(16) u16 Bt2[48][104];
    __shared__ __align__(16) u16 sh1[64][104];
    __shared__ float sb1[96];
    const int tid = threadIdx.x;
    {
        const u16* Ab = A + (size_t)blockIdx.x*64*64;
        for (int i = tid; i < 512; i += 256){
            int r = i >> 3, s = i & 7;
            *(uint4*)&As[r][s*8] = *(const uint4*)&Ab[r*64 + s*8];
        }
    }
    for (int i = tid; i < 64*96; i += 256){
        int k = i / 96, n = i % 96;
        Bt1[n][k] = (k < 58) ? w1[k*96 + n] : (u16)0;
    }
    for (int i = tid; i < 96*48; i += 256){
        int k = i / 48, n = i % 48;
        Bt2[n][k] = w2[k*48 + n];
    }
    if (tid < 96) sb1[tid] = b1[tid];
    __syncthreads();

    const int wv = tid >> 6, l = tid & 63;
    const int lr = l & 15, lg = l >> 4;
    const int r0 = wv*16;

    f32x4 acc1[6] = {};
    #pragma unroll
    for (int s = 0; s < 2; ++s){
        s16x8 af = *(const s16x8*)&As[r0+lr][s*32 + lg*8];
        #pragma unroll
        for (int t = 0; t < 6; ++t){
            s16x8 bf = *(const s16x8*)&Bt1[t*16+lr][s*32 + lg*8];
            acc1[t] = __builtin_amdgcn_mfma_f32_16x16x32_bf16(af, bf, acc1[t], 0, 0, 0);
        }
    }
    #pragma unroll
    for (int t = 0; t < 6; ++t){
        int col = t*16 + lr;
        float bias = sb1[col];
        #pragma unroll
        for (int r = 0; r < 4; ++r)
            sh1[r0 + lg*4 + r][col] = f2b(fmaxf(acc1[t][r] + bias, 0.f));
    }
    __syncthreads();

    f32x4 acc2[3] = {};
    #pragma unroll
    for (int s = 0; s < 3; ++s){
        s16x8 af = *(const s16x8*)&sh1[r0+lr][s*32 + lg*8];
        #pragma unroll
        for (int t = 0; t < 3; ++t){
            s16x8 bf = *(const s16x8*)&Bt2[t*16+lr][s*32 + lg*8];
            acc2[t] = __builtin_amdgcn_mfma_f32_16x16x32_bf16(af, bf, acc2[t], 0, 0, 0);
        }
    }
    size_t gbase = (size_t)blockIdx.x*64;
    #pragma unroll
    for (int r = 0; r < 4; ++r){
        size_t row = gbase + r0 + lg*4 + r;
        float dv = dinv[row];
        #pragma unroll
        for (int t = 0; t < 3; ++t)
            ts[row*64 + t*16 + lr] = f2b(acc2[t][r] * dv);
        ts[row*64 + 48 + lr] = 0;
    }
}

// ---------------- MFMA MLP GEMM: C = relu(A @ B + bias), 64x64 tile ----------------

__global__ __launch_bounds__(256) void k_mlp_gemm(
    const u16* __restrict__ A, int lda,
    const u16* __restrict__ B, int ldb,
    const float* __restrict__ bias,
    u16* __restrict__ C, int ldc, int K)
{
    __shared__ __align__(16) u16 As[64][72];
    __shared__ __align__(16) u16 Bt[64][72];
    const int tid = threadIdx.x;
    const int row0 = blockIdx.y*64, col0 = blockIdx.x*64;
    const int wv = tid >> 6, l = tid & 63;
    const int lr = l & 15, lg = l >> 4;
    const int r0 = wv*16;
    f32x4 acc[4] = {};
    for (int k0 = 0; k0 < K; k0 += 64){
        __syncthreads();
        for (int i = tid; i < 512; i += 256){
            int r = i >> 3, s = i & 7;
            *(uint4*)&As[r][s*8] = *(const uint4*)&A[(size_t)(row0 + r)*lda + k0 + s*8];
        }
        for (int i = tid; i < 4096; i += 256){
            int k = i >> 6, n = i & 63;
            Bt[n][k] = B[(size_t)(k0 + k)*ldb + col0 + n];
        }
        __syncthreads();
        #pragma unroll
        for (int s = 0; s < 2; ++s){
            s16x8 af = *(const s16x8*)&As[r0+lr][s*32 + lg*8];
            #pragma unroll
            for (int t = 0; t < 4; ++t){
                s16x8 bf = *(const s16x8*)&Bt[t*16+lr][s*32 + lg*8];
                acc[t] = __builtin_amdgcn_mfma_f32_16x16x32_bf16(af, bf, acc[t], 0, 0, 0);
            }
        }
    }
    #pragma unroll
    for (int t = 0; t < 4; ++t){
        int col = col0 + t*16 + lr;
        float bs = bias[col];
        #pragma unroll
        for (int r = 0; r < 4; ++r){
            size_t row = row0 + r0 + lg*4 + r;
            C[row*ldc + col] = f2b(fmaxf(acc[t][r] + bs, 0.f));
        }
    }
}

// ---------------- final: sigmoid(g2 @ w3 + b3) ----------------

__global__ void k_final(const u16* __restrict__ g2, const float* __restrict__ w3,
                        const float* __restrict__ b3, float* __restrict__ out){
    int gid  = blockIdx.x*256 + threadIdx.x;
    int row  = gid >> 6;
    int lane = gid & 63;
    float v = b2f(g2[(size_t)row*64 + lane]) * w3[lane];
    #pragma unroll
    for (int o = 32; o; o >>= 1) v += __shfl_xor(v, o);
    if (!lane) out[row] = 1.0f / (1.0f + expf(-(v + b3[0])));
}

extern "C" void kernel_launch(void* const* d_in, const int* in_sizes, int n_in,
                              void* d_out, int out_size, void* d_ws, size_t ws_size,
                              hipStream_t stream){
    const float* x   = (const float*)d_in[0];
    const int*   ei  = (const int*)  d_in[1];
    const int*   src = ei;
    const int*   dst = ei + N_EDGES;
    const float* W1  = (const float*)d_in[2];
    const float* b1  = (const float*)d_in[3];
    const float* W2  = (const float*)d_in[4];
    const float* b2  = (const float*)d_in[5];
    const float* l1w = (const float*)d_in[6];
    const float* l1b = (const float*)d_in[7];
    const float* l2w = (const float*)d_in[8];
    const float* l2b = (const float*)d_in[9];
    const float* l3w = (const float*)d_in[10];
    const float* l3b = (const float*)d_in[11];
    float* out = (float*)d_out;

    char* w = (char*)d_ws;
    auto alloc = [&](size_t bytes){ void* p = (void*)w; w += (bytes + 255) & ~(size_t)255; return p; };
    float* dinv   = (float*)alloc((size_t)N_NODES*4);
    int*   rowst  = (int*)  alloc((size_t)N_NODES*4);   // deg -> row_start (in-place scan)
    int*   cursor = (int*)  alloc((size_t)N_NODES*4);
    int*   gcur   = (int*)  alloc(NB*4);
    int*   bsum   = (int*)  alloc(4096);
    int*   bofs   = (int*)  alloc(4096);
    u16*   w1b    = (u16*)  alloc(58*96*2);
    u16*   w2b    = (u16*)  alloc(96*48*2);
    u16*   l1wb   = (u16*)  alloc((size_t)1920*256*2);
    u16*   l2wb   = (u16*)  alloc((size_t)256*64*2);
    int*   csr    = (int*)  alloc((size_t)N_EDGES*4);
    char*  BUF_A  = (char*) alloc((size_t)N_NODES*64*2);  // agg1 -> agg2
    char*  BUF_B  = (char*) alloc((size_t)N_NODES*64*2);  // staging -> xs
    char*  BUF_C  = (char*) alloc((size_t)N_NODES*64*2);  // ts

    u16*   agg1    = (u16*)BUF_A;
    u16*   agg2    = (u16*)BUF_A;        // dense 48, alive after agg1 dead
    uint2* staging = (uint2*)BUF_B;      // 21MB, dead before xs
    u16*   xs      = (u16*)BUF_B;
    u16*   ts      = (u16*)BUF_C;
    u16*   g1      = (u16*)csr;          // csr dead after gather2
    u16*   g2      = g1 + (size_t)NGRAPH*256;

    // weight conversion (independent)
    k_f2bf<<<22,   256, 0, stream>>>(W1,  w1b,  58*96);
    k_f2bf<<<18,   256, 0, stream>>>(W2,  w2b,  96*48);
    k_f2bf<<<1920, 256, 0, stream>>>(l1w, l1wb, 1920*256);
    k_f2bf<<<64,   256, 0, stream>>>(l2w, l2wb, 256*64);

    // degree + scan + bucketed CSR build
    k_zero    <<<1280, 256, 0, stream>>>(rowst, N_NODES);
    k_hist    <<<10240,256, 0, stream>>>(dst, rowst);
    k_dinv    <<<1280, 256, 0, stream>>>(rowst, dinv);
    k_scan1   <<<320,  256, 0, stream>>>(rowst, bsum);
    k_scan2   <<<1,    512, 0, stream>>>(bsum, bofs);
    k_scan3   <<<1280, 256, 0, stream>>>(rowst, bofs, cursor);
    k_gcur    <<<3,    256, 0, stream>>>(rowst, gcur);
    k_partition<<<640, 256, 0, stream>>>(src, dst, gcur, staging);
    k_finalize <<<640, 256, 0, stream>>>(staging, rowst, cursor, csr);

    // conv1: prescale, gather(64-wide), fused W1/relu/W2/dinv -> ts
    k_prescale    <<<81920, 256, 0, stream>>>(x, dinv, xs);
    k_gather<64,0><<<81920, 256, 0, stream>>>(rowst, cursor, csr, dinv, xs, nullptr, agg1);
    k_conv_mlp    <<<5120,  256, 0, stream>>>(agg1, w1b, b1, w2b, dinv, ts);

    // conv2: gather(64-wide in, 48 dense out) + b2 + relu
    k_gather<48,1><<<81920, 256, 0, stream>>>(rowst, cursor, csr, dinv, ts, b2, agg2);

    // MLP head (MFMA)
    k_mlp_gemm<<<dim3(4,128), 256, 0, stream>>>(agg2, 1920, l1wb, 256, l1b, g1, 256, 1920);
    k_mlp_gemm<<<dim3(1,128), 256, 0, stream>>>(g1,   256,  l2wb, 64,  l2b, g2, 64,  256);
    k_final   <<<2048, 256, 0, stream>>>(g2, l3w, l3b, out);
}

// Round 4
// 540.371 us; speedup vs baseline: 4.2950x; 1.3907x over previous
//
#include <hip/hip_runtime.h>

#define N_NODES 327680
#define N_EDGES 2621440
#define NGRAPH  8192
#define NB      640          // dst buckets (512 nodes each)

typedef unsigned int uint;
typedef unsigned short u16;
typedef __attribute__((ext_vector_type(8))) short s16x8;
typedef __attribute__((ext_vector_type(4))) float f32x4;

__device__ __forceinline__ float b2f(u16 h){ return __uint_as_float(((uint)h)<<16); }
__device__ __forceinline__ u16 f2b(float f){
    uint u = __float_as_uint(f);
    u += 0x7fffu + ((u>>16)&1u);          // round-to-nearest-even
    return (u16)(u>>16);
}

// ---------------- degree / scan ----------------

__global__ void k_zero(int* __restrict__ p, int n){
    int i = blockIdx.x*256 + threadIdx.x;
    if (i < n) p[i] = 0;
}

__global__ void k_hist4(const int* __restrict__ dst, int* __restrict__ deg){
    int e = (blockIdx.x*256 + threadIdx.x)*4;
    int4 d = *(const int4*)&dst[e];
    atomicAdd(&deg[d.x], 1);
    atomicAdd(&deg[d.y], 1);
    atomicAdd(&deg[d.z], 1);
    atomicAdd(&deg[d.w], 1);
}

__global__ void k_dinv(const int* __restrict__ deg, float* __restrict__ dinv){
    int i = blockIdx.x*256 + threadIdx.x;
    if (i < N_NODES) dinv[i] = 1.0f / sqrtf((float)(deg[i] + 1));  // +1 self-loop
}

__global__ __launch_bounds__(256) void k_scan1(int* __restrict__ data, int* __restrict__ bsum){
    __shared__ int ts[256];
    int base = blockIdx.x*1024 + threadIdx.x*4;
    int4 v = *(const int4*)&data[base];
    int s = v.x + v.y + v.z + v.w;
    ts[threadIdx.x] = s;
    __syncthreads();
    for (int o = 1; o < 256; o <<= 1){
        int t = (threadIdx.x >= o) ? ts[threadIdx.x - o] : 0;
        __syncthreads();
        ts[threadIdx.x] += t;
        __syncthreads();
    }
    int excl = threadIdx.x ? ts[threadIdx.x-1] : 0;
    int4 w;
    w.x = excl; w.y = w.x + v.x; w.z = w.y + v.y; w.w = w.z + v.z;
    *(int4*)&data[base] = w;
    if (threadIdx.x == 255) bsum[blockIdx.x] = ts[255];
}

__global__ __launch_bounds__(512) void k_scan2(const int* __restrict__ bsum, int* __restrict__ bofs){
    __shared__ int ts[512];
    int v = (threadIdx.x < 320) ? bsum[threadIdx.x] : 0;
    ts[threadIdx.x] = v;
    __syncthreads();
    for (int o = 1; o < 512; o <<= 1){
        int t = (threadIdx.x >= o) ? ts[threadIdx.x - o] : 0;
        __syncthreads();
        ts[threadIdx.x] += t;
        __syncthreads();
    }
    if (threadIdx.x < 320) bofs[threadIdx.x] = ts[threadIdx.x] - v;  // exclusive
}

__global__ void k_scan3(int* __restrict__ rs, const int* __restrict__ bofs, int* __restrict__ cursor){
    int i = blockIdx.x*256 + threadIdx.x;
    if (i < N_NODES){
        int v = rs[i] + bofs[i>>10];
        rs[i] = v;
        cursor[i] = v;
    }
}

// ---------------- bucketed CSR build ----------------

__global__ void k_gcur(const int* __restrict__ rowst, int* __restrict__ gcur){
    int i = blockIdx.x*256 + threadIdx.x;
    if (i < NB) gcur[i] = rowst[(size_t)i*512];
}

__global__ __launch_bounds__(256) void k_partition(
    const int* __restrict__ src, const int* __restrict__ dst,
    int* __restrict__ gcur, uint2* __restrict__ staging)
{
    __shared__ int cnt[NB], base_[NB];
    int tid = threadIdx.x;
    for (int i = tid; i < NB; i += 256) cnt[i] = 0;
    __syncthreads();
    int e0 = blockIdx.x*4096;
    int d[16];
    #pragma unroll
    for (int j = 0; j < 16; ++j){
        d[j] = dst[e0 + j*256 + tid];
        atomicAdd(&cnt[d[j] >> 9], 1);
    }
    __syncthreads();
    for (int i = tid; i < NB; i += 256)
        base_[i] = atomicAdd(&gcur[i], cnt[i]);
    __syncthreads();
    for (int i = tid; i < NB; i += 256) cnt[i] = 0;
    __syncthreads();
    #pragma unroll
    for (int j = 0; j < 16; ++j){
        int e = e0 + j*256 + tid;
        int b = d[j] >> 9;
        int r = atomicAdd(&cnt[b], 1);
        staging[base_[b] + r] = make_uint2((uint)src[e], (uint)d[j]);
    }
}

__global__ __launch_bounds__(256) void k_finalize(
    const uint2* __restrict__ staging, const int* __restrict__ rowst,
    int* __restrict__ cursor, int* __restrict__ csr)
{
    int b = blockIdx.x;
    int lo = rowst[b*512];
    int hi = (b == NB-1) ? N_EDGES : rowst[(b+1)*512];
    for (int t = lo + (int)threadIdx.x; t < hi; t += 256){
        uint2 e = staging[t];
        int pos = atomicAdd(&cursor[e.y], 1);
        csr[pos] = (int)e.x;
    }
}

// ---------------- transpose+convert: out[n][k] = bf16(in[k][n]), zero-pad k>=K ----------------

__global__ __launch_bounds__(256) void k_trconv(const float* __restrict__ in, u16* __restrict__ out,
                                                int K, int N, int Kpad){
    __shared__ u16 t[64][72];
    int kb = blockIdx.x*64, nb = blockIdx.y*64;
    for (int i = threadIdx.x; i < 4096; i += 256){
        int k = i >> 6, n = i & 63;
        int gk = kb + k, gn = nb + n;
        float v = (gk < K && gn < N) ? in[(size_t)gk*N + gn] : 0.f;
        t[n][k] = f2b(v);
    }
    __syncthreads();
    for (int i = threadIdx.x; i < 4096; i += 256){
        int n = i >> 6, k = i & 63;
        int gk = kb + k, gn = nb + n;
        if (gn < N && gk < Kpad) out[(size_t)gn*Kpad + gk] = t[n][k];
    }
}

// ---------------- prescale x*dinv -> packed bf16x2, padded to 64 cols ----------------

__global__ void k_prescale2(const float* __restrict__ x, const float* __restrict__ dinv,
                            uint* __restrict__ xs32){
    int gid = blockIdx.x*256 + threadIdx.x;
    int node = gid >> 5, c = gid & 31;
    float dv = dinv[node];
    float a = 0.f, b = 0.f;
    if (c < 29){
        float2 v = *(const float2*)&x[(size_t)node*58 + 2*c];
        a = v.x * dv; b = v.y * dv;
    }
    xs32[(size_t)node*32 + c] = (uint)f2b(a) | ((uint)f2b(b) << 16);
}

// ---------------- CSR gather: half-wave per node, packed bf16x2 lanes, unroll 4 ----------------

template<int BR>
__global__ __launch_bounds__(256) void k_gatherv(
    const int* __restrict__ rs, const int* __restrict__ rend,
    const int* __restrict__ csr, const float* __restrict__ dinv,
    const uint* __restrict__ feat32,   // [N][32] packed bf16x2
    const float* __restrict__ bias,
    u16* __restrict__ out)
{
    int gid = blockIdx.x*256 + threadIdx.x;
    int node = gid >> 5;
    int c = threadIdx.x & 31;
    uint u = feat32[(size_t)node*32 + c];
    float ax = __uint_as_float(u << 16);
    float ay = __uint_as_float(u & 0xffff0000u);
    int e = rs[node], e1 = rend[node];
    for (; e + 4 <= e1; e += 4){
        int i0 = csr[e], i1 = csr[e+1], i2 = csr[e+2], i3 = csr[e+3];
        uint u0 = feat32[(size_t)i0*32 + c];
        uint u1 = feat32[(size_t)i1*32 + c];
        uint u2 = feat32[(size_t)i2*32 + c];
        uint u3 = feat32[(size_t)i3*32 + c];
        ax += __uint_as_float(u0 << 16); ay += __uint_as_float(u0 & 0xffff0000u);
        ax += __uint_as_float(u1 << 16); ay += __uint_as_float(u1 & 0xffff0000u);
        ax += __uint_as_float(u2 << 16); ay += __uint_as_float(u2 & 0xffff0000u);
        ax += __uint_as_float(u3 << 16); ay += __uint_as_float(u3 & 0xffff0000u);
    }
    for (; e < e1; ++e){
        uint u0 = feat32[(size_t)csr[e]*32 + c];
        ax += __uint_as_float(u0 << 16); ay += __uint_as_float(u0 & 0xffff0000u);
    }
    float di = dinv[node];
    ax *= di; ay *= di;
    if (BR){
        if (c < 24){
            ax = fmaxf(ax + bias[2*c  ], 0.f);
            ay = fmaxf(ay + bias[2*c+1], 0.f);
            uint w = (uint)f2b(ax) | ((uint)f2b(ay) << 16);
            *(uint*)&out[(size_t)node*48 + 2*c] = w;
        }
    } else {
        uint w = (uint)f2b(ax) | ((uint)f2b(ay) << 16);
        *(uint*)&out[(size_t)node*64 + 2*c] = w;
    }
}

// ---------------- fused conv MLP: ts = (relu(agg1 @ W1 + b1) @ W2) * dinv  (MFMA) ----------------

__global__ __launch_bounds__(256) void k_conv_mlp(
    const u16* __restrict__ A,      // agg1 [N][64] (58 real cols, rest 0)
    const u16* __restrict__ w1t,    // [96][64] bf16 (transposed, k-padded)
    const float* __restrict__ b1,   // [96]
    const u16* __restrict__ w2t,    // [48][96] bf16 (transposed)
    const float* __restrict__ dinv,
    u16* __restrict__ ts)           // [N][64], cols>=48 zeroed here
{
    __shared__ __align__(16) u16 As[64][72];
    __shared__ __align__(16) u16 Bt1[96][72];
    __shared__ __align__(16) u16 Bt2[48][104];
    __shared__ __align__(16) u16 sh1[64][104];
    __shared__ float sb1[96];
    const int tid = threadIdx.x;
    {
        const u16* Ab = A + (size_t)blockIdx.x*64*64;
        for (int i = tid; i < 512; i += 256){
            int r = i >> 3, s = i & 7;
            *(uint4*)&As[r][s*8] = *(const uint4*)&Ab[r*64 + s*8];
        }
    }
    for (int i = tid; i < 768; i += 256){
        int n = i >> 3, s = i & 7;
        *(uint4*)&Bt1[n][s*8] = *(const uint4*)&w1t[n*64 + s*8];
    }
    for (int i = tid; i < 576; i += 256){
        int n = i / 12, s = i % 12;
        *(uint4*)&Bt2[n][s*8] = *(const uint4*)&w2t[n*96 + s*8];
    }
    if (tid < 96) sb1[tid] = b1[tid];
    __syncthreads();

    const int wv = tid >> 6, l = tid & 63;
    const int lr = l & 15, lg = l >> 4;
    const int r0 = wv*16;

    f32x4 acc1[6] = {};
    #pragma unroll
    for (int s = 0; s < 2; ++s){
        s16x8 af = *(const s16x8*)&As[r0+lr][s*32 + lg*8];
        #pragma unroll
        for (int t = 0; t < 6; ++t){
            s16x8 bf = *(const s16x8*)&Bt1[t*16+lr][s*32 + lg*8];
            acc1[t] = __builtin_amdgcn_mfma_f32_16x16x32_bf16(af, bf, acc1[t], 0, 0, 0);
        }
    }
    #pragma unroll
    for (int t = 0; t < 6; ++t){
        int col = t*16 + lr;
        float bias = sb1[col];
        #pragma unroll
        for (int r = 0; r < 4; ++r)
            sh1[r0 + lg*4 + r][col] = f2b(fmaxf(acc1[t][r] + bias, 0.f));
    }
    __syncthreads();

    f32x4 acc2[3] = {};
    #pragma unroll
    for (int s = 0; s < 3; ++s){
        s16x8 af = *(const s16x8*)&sh1[r0+lr][s*32 + lg*8];
        #pragma unroll
        for (int t = 0; t < 3; ++t){
            s16x8 bf = *(const s16x8*)&Bt2[t*16+lr][s*32 + lg*8];
            acc2[t] = __builtin_amdgcn_mfma_f32_16x16x32_bf16(af, bf, acc2[t], 0, 0, 0);
        }
    }
    size_t gbase = (size_t)blockIdx.x*64;
    #pragma unroll
    for (int r = 0; r < 4; ++r){
        size_t row = gbase + r0 + lg*4 + r;
        float dv = dinv[row];
        #pragma unroll
        for (int t = 0; t < 3; ++t)
            ts[row*64 + t*16 + lr] = f2b(acc2[t][r] * dv);
        ts[row*64 + 48 + lr] = 0;
    }
}

// ---------------- fused MLP head: 32 graphs/block, g1 in LDS, l2/l3 fused ----------------

__global__ __launch_bounds__(256) void k_head(
    const u16* __restrict__ A,      // agg2, graph rows [8192][1920] bf16
    const u16* __restrict__ l1wt,   // [256][1920]
    const float* __restrict__ l1b,
    const u16* __restrict__ l2wt,   // [64][256]
    const float* __restrict__ l2b,
    const float* __restrict__ l3w, const float* __restrict__ l3b,
    float* __restrict__ out)
{
    __shared__ __align__(16) u16 As[32][72];
    __shared__ __align__(16) u16 Bt[256][72];
    __shared__ float part[32][2];
    u16 (*sh1)[264] = (u16(*)[264])&Bt[0][0];
    const int tid = threadIdx.x;
    const int g0 = blockIdx.x*32;
    const int w = tid >> 6, l = tid & 63;
    const int lr = l & 15, lg = l >> 4;
    const int r0 = (w & 1)*16;
    const int c0 = (w >> 1)*128;
    f32x4 acc[8] = {};
    for (int k0 = 0; k0 < 1920; k0 += 64){
        __syncthreads();
        {
            int r = tid >> 3, s = tid & 7;
            *(uint4*)&As[r][s*8] = *(const uint4*)&A[(size_t)(g0+r)*1920 + k0 + s*8];
        }
        for (int i = tid; i < 2048; i += 256){
            int n = i >> 3, s = i & 7;
            *(uint4*)&Bt[n][s*8] = *(const uint4*)&l1wt[(size_t)n*1920 + k0 + s*8];
        }
        __syncthreads();
        #pragma unroll
        for (int s = 0; s < 2; ++s){
            s16x8 af = *(const s16x8*)&As[r0+lr][s*32 + lg*8];
            #pragma unroll
            for (int t = 0; t < 8; ++t){
                s16x8 bf = *(const s16x8*)&Bt[c0 + t*16 + lr][s*32 + lg*8];
                acc[t] = __builtin_amdgcn_mfma_f32_16x16x32_bf16(af, bf, acc[t], 0, 0, 0);
            }
        }
    }
    __syncthreads();   // everyone done reading Bt before overlay write
    #pragma unroll
    for (int t = 0; t < 8; ++t){
        int col = c0 + t*16 + lr;
        float bs = l1b[col];
        #pragma unroll
        for (int r = 0; r < 4; ++r)
            sh1[r0 + lg*4 + r][col] = f2b(fmaxf(acc[t][r] + bs, 0.f));
    }
    __syncthreads();
    f32x4 acc2[2] = {};
    #pragma unroll
    for (int s = 0; s < 8; ++s){
        s16x8 af = *(const s16x8*)&sh1[r0+lr][s*32 + lg*8];
        #pragma unroll
        for (int t = 0; t < 2; ++t){
            int col = (w>>1)*32 + t*16 + lr;
            s16x8 bf = *(const s16x8*)&l2wt[(size_t)col*256 + s*32 + lg*8];
            acc2[t] = __builtin_amdgcn_mfma_f32_16x16x32_bf16(af, bf, acc2[t], 0, 0, 0);
        }
    }
    float p[4];
    #pragma unroll
    for (int r = 0; r < 4; ++r){
        p[r] = 0.f;
        #pragma unroll
        for (int t = 0; t < 2; ++t){
            int col = (w>>1)*32 + t*16 + lr;
            p[r] += fmaxf(acc2[t][r] + l2b[col], 0.f) * l3w[col];
        }
    }
    #pragma unroll
    for (int o = 1; o < 16; o <<= 1){
        #pragma unroll
        for (int r = 0; r < 4; ++r) p[r] += __shfl_xor(p[r], o);
    }
    if (lr == 0){
        #pragma unroll
        for (int r = 0; r < 4; ++r)
            part[r0 + lg*4 + r][w>>1] = p[r];
    }
    __syncthreads();
    if (tid < 32)
        out[g0 + tid] = 1.0f / (1.0f + expf(-(part[tid][0] + part[tid][1] + l3b[0])));
}

extern "C" void kernel_launch(void* const* d_in, const int* in_sizes, int n_in,
                              void* d_out, int out_size, void* d_ws, size_t ws_size,
                              hipStream_t stream){
    const float* x   = (const float*)d_in[0];
    const int*   ei  = (const int*)  d_in[1];
    const int*   src = ei;
    const int*   dst = ei + N_EDGES;
    const float* W1  = (const float*)d_in[2];
    const float* b1  = (const float*)d_in[3];
    const float* W2  = (const float*)d_in[4];
    const float* b2  = (const float*)d_in[5];
    const float* l1w = (const float*)d_in[6];
    const float* l1b = (const float*)d_in[7];
    const float* l2w = (const float*)d_in[8];
    const float* l2b = (const float*)d_in[9];
    const float* l3w = (const float*)d_in[10];
    const float* l3b = (const float*)d_in[11];
    float* out = (float*)d_out;

    char* w = (char*)d_ws;
    auto alloc = [&](size_t bytes){ void* p = (void*)w; w += (bytes + 255) & ~(size_t)255; return p; };
    float* dinv   = (float*)alloc((size_t)N_NODES*4);
    int*   rowst  = (int*)  alloc((size_t)N_NODES*4);
    int*   cursor = (int*)  alloc((size_t)N_NODES*4);
    int*   gcur   = (int*)  alloc(NB*4);
    int*   bsum   = (int*)  alloc(4096);
    int*   bofs   = (int*)  alloc(4096);
    u16*   w1t    = (u16*)  alloc(96*64*2);
    u16*   w2t    = (u16*)  alloc(48*96*2);
    u16*   l1wt   = (u16*)  alloc((size_t)256*1920*2);
    u16*   l2wt   = (u16*)  alloc((size_t)64*256*2);
    int*   csr    = (int*)  alloc((size_t)N_EDGES*4);
    char*  BUF_A  = (char*) alloc((size_t)N_NODES*64*2);  // agg1 -> agg2
    char*  BUF_B  = (char*) alloc((size_t)N_NODES*64*2);  // staging -> xs
    char*  BUF_C  = (char*) alloc((size_t)N_NODES*64*2);  // ts

    u16*   agg1    = (u16*)BUF_A;
    u16*   agg2    = (u16*)BUF_A;        // dense 48 per node == graph-major [8192][1920]
    uint2* staging = (uint2*)BUF_B;      // dead before xs
    uint*  xs32    = (uint*)BUF_B;
    u16*   ts      = (u16*)BUF_C;

    // weight transposes (independent, tiny)
    k_trconv<<<dim3(1,2),  256, 0, stream>>>(W1,  w1t,  58,   96,  64);
    k_trconv<<<dim3(2,1),  256, 0, stream>>>(W2,  w2t,  96,   48,  96);
    k_trconv<<<dim3(30,4), 256, 0, stream>>>(l1w, l1wt, 1920, 256, 1920);
    k_trconv<<<dim3(4,1),  256, 0, stream>>>(l2w, l2wt, 256,  64,  256);

    // degree + scan + bucketed CSR build
    k_zero    <<<1280, 256, 0, stream>>>(rowst, N_NODES);
    k_hist4   <<<2560, 256, 0, stream>>>(dst, rowst);
    k_dinv    <<<1280, 256, 0, stream>>>(rowst, dinv);
    k_scan1   <<<320,  256, 0, stream>>>(rowst, bsum);
    k_scan2   <<<1,    512, 0, stream>>>(bsum, bofs);
    k_scan3   <<<1280, 256, 0, stream>>>(rowst, bofs, cursor);
    k_gcur    <<<3,    256, 0, stream>>>(rowst, gcur);
    k_partition<<<640, 256, 0, stream>>>(src, dst, gcur, staging);
    k_finalize <<<640, 256, 0, stream>>>(staging, rowst, cursor, csr);

    // conv1
    k_prescale2    <<<40960, 256, 0, stream>>>(x, dinv, xs32);
    k_gatherv<0>   <<<40960, 256, 0, stream>>>(rowst, cursor, csr, dinv, xs32, nullptr, agg1);
    k_conv_mlp     <<<5120,  256, 0, stream>>>(agg1, w1t, b1, w2t, dinv, ts);

    // conv2
    k_gatherv<1>   <<<40960, 256, 0, stream>>>(rowst, cursor, csr, dinv, (const uint*)ts, b2, agg2);

    // fused MLP head
    k_head         <<<256,   256, 0, stream>>>(agg2, l1wt, l1b, l2wt, l2b, l3w, l3b, out);
}

// Round 5
// 378.297 us; speedup vs baseline: 6.1352x; 1.4284x over previous
//
#include <hip/hip_runtime.h>

#define N_NODES 327680
#define N_EDGES 2621440
#define NGRAPH  8192
#define NB      640          // dst buckets (512 nodes each)
#define BCAP    4608         // LDS edge cache per bucket (mean 4096, sigma ~64)

typedef unsigned int uint;
typedef unsigned short u16;
typedef __attribute__((ext_vector_type(8))) short s16x8;
typedef __attribute__((ext_vector_type(4))) float f32x4;

__device__ __forceinline__ float b2f(u16 h){ return __uint_as_float(((uint)h)<<16); }
__device__ __forceinline__ u16 f2b(float f){
    uint u = __float_as_uint(f);
    u += 0x7fffu + ((u>>16)&1u);          // round-to-nearest-even
    return (u16)(u>>16);
}

// ---------------- bucket histogram / scan ----------------

__global__ void k_zero(int* __restrict__ p, int n){
    int i = blockIdx.x*256 + threadIdx.x;
    if (i < n) p[i] = 0;
}

__global__ __launch_bounds__(256) void k_bhist(const int* __restrict__ dst, int* __restrict__ bcnt){
    __shared__ int cnt[NB];
    int tid = threadIdx.x;
    for (int i = tid; i < NB; i += 256) cnt[i] = 0;
    __syncthreads();
    int e0 = blockIdx.x*4096;
    #pragma unroll
    for (int j = 0; j < 16; ++j)
        atomicAdd(&cnt[dst[e0 + j*256 + tid] >> 9], 1);
    __syncthreads();
    for (int i = tid; i < NB; i += 256){
        int v = cnt[i];
        if (v) atomicAdd(&bcnt[i], v);
    }
}

__global__ __launch_bounds__(1024) void k_bscan(const int* __restrict__ bcnt,
                                                int* __restrict__ bbase, int* __restrict__ gcur){
    __shared__ int ts[1024];
    int tid = threadIdx.x;
    int v = (tid < NB) ? bcnt[tid] : 0;
    ts[tid] = v;
    __syncthreads();
    for (int o = 1; o < 1024; o <<= 1){
        int t = (tid >= o) ? ts[tid-o] : 0;
        __syncthreads();
        ts[tid] += t;
        __syncthreads();
    }
    if (tid < NB){
        int ex = ts[tid] - v;
        bbase[tid] = ex;
        gcur[tid] = ex;
    }
}

// ---------------- partition edges into dst-buckets ----------------

__global__ __launch_bounds__(256) void k_partition(
    const int* __restrict__ src, const int* __restrict__ dst,
    int* __restrict__ gcur, uint2* __restrict__ staging)
{
    __shared__ int cnt[NB], base_[NB];
    int tid = threadIdx.x;
    for (int i = tid; i < NB; i += 256) cnt[i] = 0;
    __syncthreads();
    int e0 = blockIdx.x*4096;
    int d[16];
    #pragma unroll
    for (int j = 0; j < 16; ++j){
        d[j] = dst[e0 + j*256 + tid];
        atomicAdd(&cnt[d[j] >> 9], 1);
    }
    __syncthreads();
    for (int i = tid; i < NB; i += 256)
        base_[i] = atomicAdd(&gcur[i], cnt[i]);
    __syncthreads();
    for (int i = tid; i < NB; i += 256) cnt[i] = 0;
    __syncthreads();
    #pragma unroll
    for (int j = 0; j < 16; ++j){
        int e = e0 + j*256 + tid;
        int b = d[j] >> 9;
        int r = atomicAdd(&cnt[b], 1);
        staging[base_[b] + r] = make_uint2((uint)src[e], (uint)d[j]);
    }
}

// ---------------- per-bucket: degree, dinv, row starts, csr place (all LDS-local) ----------------

__global__ __launch_bounds__(512) void k_bucket(
    const uint2* __restrict__ staging, const int* __restrict__ bbase,
    int* __restrict__ rowst, int* __restrict__ rendg, float* __restrict__ dinvg,
    int* __restrict__ csr)
{
    __shared__ uint2 sedge[BCAP];
    __shared__ int deg[512];
    __shared__ int sc[512];
    __shared__ int cur[512];
    const int b = blockIdx.x;
    const int tid = threadIdx.x;
    const int lo = bbase[b];
    const int hi = (b == NB-1) ? N_EDGES : bbase[b+1];
    const int cnt = hi - lo;
    deg[tid] = 0;
    __syncthreads();
    for (int t = tid; t < cnt; t += 512){
        uint2 ed = staging[lo + t];
        if (t < BCAP) sedge[t] = ed;
        atomicAdd(&deg[ed.y & 511], 1);
    }
    __syncthreads();
    int d = deg[tid];
    sc[tid] = d;
    __syncthreads();
    for (int o = 1; o < 512; o <<= 1){
        int v = (tid >= o) ? sc[tid-o] : 0;
        __syncthreads();
        sc[tid] += v;
        __syncthreads();
    }
    int incl = sc[tid];
    int excl = incl - d;
    int gnode = b*512 + tid;
    rowst[gnode] = lo + excl;
    rendg[gnode] = lo + incl;
    dinvg[gnode] = 1.0f / sqrtf((float)(d + 1));
    cur[tid] = lo + excl;
    __syncthreads();
    for (int t = tid; t < cnt; t += 512){
        uint2 ed = (t < BCAP) ? sedge[t] : staging[lo + t];
        int pos = atomicAdd(&cur[ed.y & 511], 1);
        csr[pos] = (int)ed.x;
    }
}

// ---------------- transpose+convert: out[n][k] = bf16(in[k][n]), zero-pad k>=K ----------------

__global__ __launch_bounds__(256) void k_trconv(const float* __restrict__ in, u16* __restrict__ out,
                                                int K, int N, int Kpad){
    __shared__ u16 t[64][72];
    int kb = blockIdx.x*64, nb = blockIdx.y*64;
    for (int i = threadIdx.x; i < 4096; i += 256){
        int k = i >> 6, n = i & 63;
        int gk = kb + k, gn = nb + n;
        float v = (gk < K && gn < N) ? in[(size_t)gk*N + gn] : 0.f;
        t[n][k] = f2b(v);
    }
    __syncthreads();
    for (int i = threadIdx.x; i < 4096; i += 256){
        int n = i >> 6, k = i & 63;
        int gk = kb + k, gn = nb + n;
        if (gn < N && gk < Kpad) out[(size_t)gn*Kpad + gk] = t[n][k];
    }
}

// ---------------- prescale x*dinv -> packed bf16x2, padded to 64 cols ----------------

__global__ void k_prescale2(const float* __restrict__ x, const float* __restrict__ dinv,
                            uint* __restrict__ xs32){
    int gid = blockIdx.x*256 + threadIdx.x;
    int node = gid >> 5, c = gid & 31;
    float dv = dinv[node];
    float a = 0.f, b = 0.f;
    if (c < 29){
        float2 v = *(const float2*)&x[(size_t)node*58 + 2*c];
        a = v.x * dv; b = v.y * dv;
    }
    xs32[(size_t)node*32 + c] = (uint)f2b(a) | ((uint)f2b(b) << 16);
}

// ---------------- CSR gather: half-wave/node, clamped quads + next-quad prefetch ----------------

template<int BR>
__global__ __launch_bounds__(256) void k_gatherv(
    const int* __restrict__ rs, const int* __restrict__ rend,
    const int* __restrict__ csr, const float* __restrict__ dinv,
    const uint* __restrict__ feat32,   // [N][32] packed bf16x2
    const float* __restrict__ bias,
    u16* __restrict__ out)
{
    int gid = blockIdx.x*256 + threadIdx.x;
    int node = gid >> 5;
    int c = threadIdx.x & 31;
    uint u = feat32[(size_t)node*32 + c];
    float ax = __uint_as_float(u << 16);
    float ay = __uint_as_float(u & 0xffff0000u);
    int e  = rs[node];
    const int e1 = rend[node];
    if (e < e1){
        const int last = e1 - 1;
        int i0 = csr[e];
        int i1 = csr[min(e+1, last)];
        int i2 = csr[min(e+2, last)];
        int i3 = csr[min(e+3, last)];
        for (;;){
            int en = e + 4;
            bool more = en < e1;
            int j0=0, j1=0, j2=0, j3=0;
            if (more){
                j0 = csr[en];
                j1 = csr[min(en+1, last)];
                j2 = csr[min(en+2, last)];
                j3 = csr[min(en+3, last)];
            }
            uint u0 = feat32[(size_t)i0*32 + c];
            uint u1 = feat32[(size_t)i1*32 + c];
            uint u2 = feat32[(size_t)i2*32 + c];
            uint u3 = feat32[(size_t)i3*32 + c];
            if (e+1 >= e1) u1 = 0;
            if (e+2 >= e1) u2 = 0;
            if (e+3 >= e1) u3 = 0;
            ax += __uint_as_float(u0 << 16); ay += __uint_as_float(u0 & 0xffff0000u);
            ax += __uint_as_float(u1 << 16); ay += __uint_as_float(u1 & 0xffff0000u);
            ax += __uint_as_float(u2 << 16); ay += __uint_as_float(u2 & 0xffff0000u);
            ax += __uint_as_float(u3 << 16); ay += __uint_as_float(u3 & 0xffff0000u);
            if (!more) break;
            i0 = j0; i1 = j1; i2 = j2; i3 = j3;
            e = en;
        }
    }
    float di = dinv[node];
    ax *= di; ay *= di;
    if (BR){
        if (c < 24){
            ax = fmaxf(ax + bias[2*c  ], 0.f);
            ay = fmaxf(ay + bias[2*c+1], 0.f);
            uint w = (uint)f2b(ax) | ((uint)f2b(ay) << 16);
            *(uint*)&out[(size_t)node*48 + 2*c] = w;
        }
    } else {
        uint w = (uint)f2b(ax) | ((uint)f2b(ay) << 16);
        *(uint*)&out[(size_t)node*64 + 2*c] = w;
    }
}

// ---------------- fused conv MLP: ts = (relu(agg1 @ W1 + b1) @ W2) * dinv  (MFMA) ----------------

__global__ __launch_bounds__(256) void k_conv_mlp(
    const u16* __restrict__ A,      // agg1 [N][64] (58 real cols, rest 0)
    const u16* __restrict__ w1t,    // [96][64] bf16 (transposed, k-padded)
    const float* __restrict__ b1,   // [96]
    const u16* __restrict__ w2t,    // [48][96] bf16 (transposed)
    const float* __restrict__ dinv,
    u16* __restrict__ ts)           // [N][64], cols>=48 zeroed here
{
    __shared__ __align__(16) u16 As[64][72];
    __shared__ __align__(16) u16 Bt1[96][72];
    __shared__ __align__(16) u16 Bt2[48][104];
    __shared__ __align__(16) u16 sh1[64][104];
    __shared__ float sb1[96];
    const int tid = threadIdx.x;
    {
        const u16* Ab = A + (size_t)blockIdx.x*64*64;
        for (int i = tid; i < 512; i += 256){
            int r = i >> 3, s = i & 7;
            *(uint4*)&As[r][s*8] = *(const uint4*)&Ab[r*64 + s*8];
        }
    }
    for (int i = tid; i < 768; i += 256){
        int n = i >> 3, s = i & 7;
        *(uint4*)&Bt1[n][s*8] = *(const uint4*)&w1t[n*64 + s*8];
    }
    for (int i = tid; i < 576; i += 256){
        int n = i / 12, s = i % 12;
        *(uint4*)&Bt2[n][s*8] = *(const uint4*)&w2t[n*96 + s*8];
    }
    if (tid < 96) sb1[tid] = b1[tid];
    __syncthreads();

    const int wv = tid >> 6, l = tid & 63;
    const int lr = l & 15, lg = l >> 4;
    const int r0 = wv*16;

    f32x4 acc1[6] = {};
    #pragma unroll
    for (int s = 0; s < 2; ++s){
        s16x8 af = *(const s16x8*)&As[r0+lr][s*32 + lg*8];
        #pragma unroll
        for (int t = 0; t < 6; ++t){
            s16x8 bf = *(const s16x8*)&Bt1[t*16+lr][s*32 + lg*8];
            acc1[t] = __builtin_amdgcn_mfma_f32_16x16x32_bf16(af, bf, acc1[t], 0, 0, 0);
        }
    }
    #pragma unroll
    for (int t = 0; t < 6; ++t){
        int col = t*16 + lr;
        float bias = sb1[col];
        #pragma unroll
        for (int r = 0; r < 4; ++r)
            sh1[r0 + lg*4 + r][col] = f2b(fmaxf(acc1[t][r] + bias, 0.f));
    }
    __syncthreads();

    f32x4 acc2[3] = {};
    #pragma unroll
    for (int s = 0; s < 3; ++s){
        s16x8 af = *(const s16x8*)&sh1[r0+lr][s*32 + lg*8];
        #pragma unroll
        for (int t = 0; t < 3; ++t){
            s16x8 bf = *(const s16x8*)&Bt2[t*16+lr][s*32 + lg*8];
            acc2[t] = __builtin_amdgcn_mfma_f32_16x16x32_bf16(af, bf, acc2[t], 0, 0, 0);
        }
    }
    size_t gbase = (size_t)blockIdx.x*64;
    #pragma unroll
    for (int r = 0; r < 4; ++r){
        size_t row = gbase + r0 + lg*4 + r;
        float dv = dinv[row];
        #pragma unroll
        for (int t = 0; t < 3; ++t)
            ts[row*64 + t*16 + lr] = f2b(acc2[t][r] * dv);
        ts[row*64 + 48 + lr] = 0;
    }
}

// ---------------- fused MLP head: 32 graphs/block, g1 in LDS, l2/l3 fused ----------------

__global__ __launch_bounds__(256) void k_head(
    const u16* __restrict__ A,      // agg2, graph rows [8192][1920] bf16
    const u16* __restrict__ l1wt,   // [256][1920]
    const float* __restrict__ l1b,
    const u16* __restrict__ l2wt,   // [64][256]
    const float* __restrict__ l2b,
    const float* __restrict__ l3w, const float* __restrict__ l3b,
    float* __restrict__ out)
{
    __shared__ __align__(16) u16 As[32][72];
    __shared__ __align__(16) u16 Bt[256][72];
    __shared__ float part[32][2];
    u16 (*sh1)[264] = (u16(*)[264])&Bt[0][0];
    const int tid = threadIdx.x;
    const int g0 = blockIdx.x*32;
    const int w = tid >> 6, l = tid & 63;
    const int lr = l & 15, lg = l >> 4;
    const int r0 = (w & 1)*16;
    const int c0 = (w >> 1)*128;
    f32x4 acc[8] = {};
    for (int k0 = 0; k0 < 1920; k0 += 64){
        __syncthreads();
        {
            int r = tid >> 3, s = tid & 7;
            *(uint4*)&As[r][s*8] = *(const uint4*)&A[(size_t)(g0+r)*1920 + k0 + s*8];
        }
        for (int i = tid; i < 2048; i += 256){
            int n = i >> 3, s = i & 7;
            *(uint4*)&Bt[n][s*8] = *(const uint4*)&l1wt[(size_t)n*1920 + k0 + s*8];
        }
        __syncthreads();
        #pragma unroll
        for (int s = 0; s < 2; ++s){
            s16x8 af = *(const s16x8*)&As[r0+lr][s*32 + lg*8];
            #pragma unroll
            for (int t = 0; t < 8; ++t){
                s16x8 bf = *(const s16x8*)&Bt[c0 + t*16 + lr][s*32 + lg*8];
                acc[t] = __builtin_amdgcn_mfma_f32_16x16x32_bf16(af, bf, acc[t], 0, 0, 0);
            }
        }
    }
    __syncthreads();   // everyone done reading Bt before overlay write
    #pragma unroll
    for (int t = 0; t < 8; ++t){
        int col = c0 + t*16 + lr;
        float bs = l1b[col];
        #pragma unroll
        for (int r = 0; r < 4; ++r)
            sh1[r0 + lg*4 + r][col] = f2b(fmaxf(acc[t][r] + bs, 0.f));
    }
    __syncthreads();
    f32x4 acc2[2] = {};
    #pragma unroll
    for (int s = 0; s < 8; ++s){
        s16x8 af = *(const s16x8*)&sh1[r0+lr][s*32 + lg*8];
        #pragma unroll
        for (int t = 0; t < 2; ++t){
            int col = (w>>1)*32 + t*16 + lr;
            s16x8 bf = *(const s16x8*)&l2wt[(size_t)col*256 + s*32 + lg*8];
            acc2[t] = __builtin_amdgcn_mfma_f32_16x16x32_bf16(af, bf, acc2[t], 0, 0, 0);
        }
    }
    float p[4];
    #pragma unroll
    for (int r = 0; r < 4; ++r){
        p[r] = 0.f;
        #pragma unroll
        for (int t = 0; t < 2; ++t){
            int col = (w>>1)*32 + t*16 + lr;
            p[r] += fmaxf(acc2[t][r] + l2b[col], 0.f) * l3w[col];
        }
    }
    #pragma unroll
    for (int o = 1; o < 16; o <<= 1){
        #pragma unroll
        for (int r = 0; r < 4; ++r) p[r] += __shfl_xor(p[r], o);
    }
    if (lr == 0){
        #pragma unroll
        for (int r = 0; r < 4; ++r)
            part[r0 + lg*4 + r][w>>1] = p[r];
    }
    __syncthreads();
    if (tid < 32)
        out[g0 + tid] = 1.0f / (1.0f + expf(-(part[tid][0] + part[tid][1] + l3b[0])));
}

extern "C" void kernel_launch(void* const* d_in, const int* in_sizes, int n_in,
                              void* d_out, int out_size, void* d_ws, size_t ws_size,
                              hipStream_t stream){
    const float* x   = (const float*)d_in[0];
    const int*   ei  = (const int*)  d_in[1];
    const int*   src = ei;
    const int*   dst = ei + N_EDGES;
    const float* W1  = (const float*)d_in[2];
    const float* b1  = (const float*)d_in[3];
    const float* W2  = (const float*)d_in[4];
    const float* b2  = (const float*)d_in[5];
    const float* l1w = (const float*)d_in[6];
    const float* l1b = (const float*)d_in[7];
    const float* l2w = (const float*)d_in[8];
    const float* l2b = (const float*)d_in[9];
    const float* l3w = (const float*)d_in[10];
    const float* l3b = (const float*)d_in[11];
    float* out = (float*)d_out;

    char* w = (char*)d_ws;
    auto alloc = [&](size_t bytes){ void* p = (void*)w; w += (bytes + 255) & ~(size_t)255; return p; };
    float* dinv   = (float*)alloc((size_t)N_NODES*4);
    int*   rowst  = (int*)  alloc((size_t)N_NODES*4);
    int*   rend   = (int*)  alloc((size_t)N_NODES*4);
    int*   bcnt   = (int*)  alloc(NB*4);
    int*   bbase  = (int*)  alloc(NB*4);
    int*   gcur   = (int*)  alloc(NB*4);
    u16*   w1t    = (u16*)  alloc(96*64*2);
    u16*   w2t    = (u16*)  alloc(48*96*2);
    u16*   l1wt   = (u16*)  alloc((size_t)256*1920*2);
    u16*   l2wt   = (u16*)  alloc((size_t)64*256*2);
    int*   csr    = (int*)  alloc((size_t)N_EDGES*4);
    char*  BUF_A  = (char*) alloc((size_t)N_NODES*64*2);  // agg1 -> agg2
    char*  BUF_B  = (char*) alloc((size_t)N_NODES*64*2);  // staging -> xs
    char*  BUF_C  = (char*) alloc((size_t)N_NODES*64*2);  // ts

    u16*   agg1    = (u16*)BUF_A;
    u16*   agg2    = (u16*)BUF_A;        // dense 48 per node == graph-major [8192][1920]
    uint2* staging = (uint2*)BUF_B;      // dead before xs
    uint*  xs32    = (uint*)BUF_B;
    u16*   ts      = (u16*)BUF_C;

    // weight transposes (independent, tiny)
    k_trconv<<<dim3(1,2),  256, 0, stream>>>(W1,  w1t,  58,   96,  64);
    k_trconv<<<dim3(2,1),  256, 0, stream>>>(W2,  w2t,  96,   48,  96);
    k_trconv<<<dim3(30,4), 256, 0, stream>>>(l1w, l1wt, 1920, 256, 1920);
    k_trconv<<<dim3(4,1),  256, 0, stream>>>(l2w, l2wt, 256,  64,  256);

    // bucketed CSR build (no hot global atomics)
    k_zero     <<<3,   256,  0, stream>>>(bcnt, NB);
    k_bhist    <<<640, 256,  0, stream>>>(dst, bcnt);
    k_bscan    <<<1,   1024, 0, stream>>>(bcnt, bbase, gcur);
    k_partition<<<640, 256,  0, stream>>>(src, dst, gcur, staging);
    k_bucket   <<<640, 512,  0, stream>>>(staging, bbase, rowst, rend, dinv, csr);

    // conv1
    k_prescale2    <<<40960, 256, 0, stream>>>(x, dinv, xs32);
    k_gatherv<0>   <<<40960, 256, 0, stream>>>(rowst, rend, csr, dinv, xs32, nullptr, agg1);
    k_conv_mlp     <<<5120,  256, 0, stream>>>(agg1, w1t, b1, w2t, dinv, ts);

    // conv2
    k_gatherv<1>   <<<40960, 256, 0, stream>>>(rowst, rend, csr, dinv, (const uint*)ts, b2, agg2);

    // fused MLP head
    k_head         <<<256,   256, 0, stream>>>(agg2, l1wt, l1b, l2wt, l2b, l3w, l3b, out);
}

// Round 6
// 363.420 us; speedup vs baseline: 6.3863x; 1.0409x over previous
//
#include <hip/hip_runtime.h>

#define N_NODES 327680
#define N_EDGES 2621440
#define NGRAPH  8192
#define NB      640          // dst buckets (512 nodes each)
#define BCAPE   4608         // fixed per-bucket capacity (mean 4096, +8 sigma)

typedef unsigned int uint;
typedef unsigned short u16;
typedef __attribute__((ext_vector_type(8))) short s16x8;
typedef __attribute__((ext_vector_type(4))) float f32x4;

__device__ __forceinline__ float b2f(u16 h){ return __uint_as_float(((uint)h)<<16); }
__device__ __forceinline__ u16 f2b(float f){
    uint u = __float_as_uint(f);
    u += 0x7fffu + ((u>>16)&1u);          // round-to-nearest-even
    return (u16)(u>>16);
}

// ---------------- bucket cursors (fixed bases) ----------------

__global__ void k_initgcur(int* __restrict__ gcur){
    int i = blockIdx.x*256 + threadIdx.x;
    if (i < NB) gcur[i] = i*BCAPE;
}

// ---------------- partition edges into fixed-cap dst-buckets ----------------

__global__ __launch_bounds__(256) void k_partition(
    const int* __restrict__ src, const int* __restrict__ dst,
    int* __restrict__ gcur, uint2* __restrict__ staging)
{
    __shared__ int cnt[NB], base_[NB];
    int tid = threadIdx.x;
    for (int i = tid; i < NB; i += 256) cnt[i] = 0;
    __syncthreads();
    int e0 = blockIdx.x*4096;
    int d[16];
    #pragma unroll
    for (int j = 0; j < 16; ++j){
        d[j] = dst[e0 + j*256 + tid];
        atomicAdd(&cnt[d[j] >> 9], 1);
    }
    __syncthreads();
    for (int i = tid; i < NB; i += 256)
        base_[i] = atomicAdd(&gcur[i], cnt[i]);
    __syncthreads();
    for (int i = tid; i < NB; i += 256) cnt[i] = 0;
    __syncthreads();
    #pragma unroll
    for (int j = 0; j < 16; ++j){
        int e = e0 + j*256 + tid;
        int b = d[j] >> 9;
        int r = atomicAdd(&cnt[b], 1);
        staging[base_[b] + r] = make_uint2((uint)src[e], (uint)d[j]);
    }
}

// ---- per-bucket: degree, dinv, row starts, csr place, degree-sorted perm (LDS-local) ----

__global__ __launch_bounds__(512) void k_bucket(
    const uint2* __restrict__ staging, const int* __restrict__ gcur,
    int* __restrict__ rowst, int* __restrict__ rendg, float* __restrict__ dinvg,
    int* __restrict__ csr, int* __restrict__ perm)
{
    __shared__ uint2 sedge[BCAPE];
    __shared__ int deg[512];
    __shared__ int sc[512];
    __shared__ int cur[512];
    __shared__ int dh[64], dbase[64];
    const int b = blockIdx.x;
    const int tid = threadIdx.x;
    const int lo = b*BCAPE;
    int cnt = gcur[b] - lo;
    if (cnt > BCAPE) cnt = BCAPE;   // safety (8-sigma margin, never expected)
    deg[tid] = 0;
    if (tid < 64) dh[tid] = 0;
    __syncthreads();
    for (int t = tid; t < cnt; t += 512){
        uint2 ed = staging[lo + t];
        sedge[t] = ed;
        atomicAdd(&deg[ed.y & 511], 1);
    }
    __syncthreads();
    int d = deg[tid];
    sc[tid] = d;
    __syncthreads();
    for (int o = 1; o < 512; o <<= 1){
        int v = (tid >= o) ? sc[tid-o] : 0;
        __syncthreads();
        sc[tid] += v;
        __syncthreads();
    }
    int incl = sc[tid];
    int excl = incl - d;
    int gnode = b*512 + tid;
    rowst[gnode] = lo + excl;
    rendg[gnode] = lo + incl;
    dinvg[gnode] = 1.0f / sqrtf((float)(d + 1));
    cur[tid] = lo + excl;
    int bin = min(d, 63);
    atomicAdd(&dh[bin], 1);
    __syncthreads();
    if (tid == 0){
        int a = 0;
        #pragma unroll
        for (int i = 0; i < 64; ++i){ dbase[i] = a; a += dh[i]; dh[i] = 0; }
    }
    __syncthreads();
    int pos = dbase[bin] + atomicAdd(&dh[bin], 1);
    perm[b*512 + pos] = gnode;
    for (int t = tid; t < cnt; t += 512){
        uint2 ed = sedge[t];
        int p = atomicAdd(&cur[ed.y & 511], 1);
        csr[p] = (int)ed.x;
    }
}

// ---------------- transpose+convert: out[n][k] = bf16(in[k][n]), zero-pad k>=K ----------------

__global__ __launch_bounds__(256) void k_trconv(const float* __restrict__ in, u16* __restrict__ out,
                                                int K, int N, int Kpad){
    __shared__ u16 t[64][72];
    int kb = blockIdx.x*64, nb = blockIdx.y*64;
    for (int i = threadIdx.x; i < 4096; i += 256){
        int k = i >> 6, n = i & 63;
        int gk = kb + k, gn = nb + n;
        float v = (gk < K && gn < N) ? in[(size_t)gk*N + gn] : 0.f;
        t[n][k] = f2b(v);
    }
    __syncthreads();
    for (int i = threadIdx.x; i < 4096; i += 256){
        int n = i >> 6, k = i & 63;
        int gk = kb + k, gn = nb + n;
        if (gn < N && gk < Kpad) out[(size_t)gn*Kpad + gk] = t[n][k];
    }
}

// ---------------- prescale x*dinv -> packed bf16x2, padded to 64 cols ----------------

__global__ void k_prescale2(const float* __restrict__ x, const float* __restrict__ dinv,
                            uint* __restrict__ xs32){
    int gid = blockIdx.x*256 + threadIdx.x;
    int node = gid >> 5, c = gid & 31;
    float dv = dinv[node];
    float a = 0.f, b = 0.f;
    if (c < 29){
        float2 v = *(const float2*)&x[(size_t)node*58 + 2*c];
        a = v.x * dv; b = v.y * dv;
    }
    xs32[(size_t)node*32 + c] = (uint)f2b(a) | ((uint)f2b(b) << 16);
}

// ---- CSR gather: 16 lanes/node x uint2, degree-sorted perm, quad prefetch ----

template<int BR>
__global__ __launch_bounds__(256) void k_gatherv(
    const int* __restrict__ rs, const int* __restrict__ re,
    const int* __restrict__ csr, const float* __restrict__ dinv,
    const int* __restrict__ perm,
    const uint2* __restrict__ feat2,   // [N][16] packed bf16x4
    const float* __restrict__ bias,
    u16* __restrict__ out)
{
    int slot = (blockIdx.x*256 + threadIdx.x) >> 4;
    int c2 = threadIdx.x & 15;
    int node = perm[slot];
    uint2 u = feat2[((uint)node << 4) + c2];
    float a0 = __uint_as_float(u.x << 16);
    float a1 = __uint_as_float(u.x & 0xffff0000u);
    float a2 = __uint_as_float(u.y << 16);
    float a3 = __uint_as_float(u.y & 0xffff0000u);
    int e = rs[node];
    const int e1 = re[node];
    if (e < e1){
        const int last = e1 - 1;
        int i0 = csr[e];
        int i1 = csr[min(e+1, last)];
        int i2 = csr[min(e+2, last)];
        int i3 = csr[min(e+3, last)];
        for (;;){
            int en = e + 4;
            bool more = en < e1;
            int j0=0, j1=0, j2=0, j3=0;
            if (more){
                j0 = csr[en];
                j1 = csr[min(en+1, last)];
                j2 = csr[min(en+2, last)];
                j3 = csr[min(en+3, last)];
            }
            uint2 u0 = feat2[((uint)i0 << 4) + c2];
            uint2 u1 = feat2[((uint)i1 << 4) + c2];
            uint2 u2 = feat2[((uint)i2 << 4) + c2];
            uint2 u3 = feat2[((uint)i3 << 4) + c2];
            if (e+1 >= e1){ u1.x = 0; u1.y = 0; }
            if (e+2 >= e1){ u2.x = 0; u2.y = 0; }
            if (e+3 >= e1){ u3.x = 0; u3.y = 0; }
            a0 += __uint_as_float(u0.x << 16); a1 += __uint_as_float(u0.x & 0xffff0000u);
            a2 += __uint_as_float(u0.y << 16); a3 += __uint_as_float(u0.y & 0xffff0000u);
            a0 += __uint_as_float(u1.x << 16); a1 += __uint_as_float(u1.x & 0xffff0000u);
            a2 += __uint_as_float(u1.y << 16); a3 += __uint_as_float(u1.y & 0xffff0000u);
            a0 += __uint_as_float(u2.x << 16); a1 += __uint_as_float(u2.x & 0xffff0000u);
            a2 += __uint_as_float(u2.y << 16); a3 += __uint_as_float(u2.y & 0xffff0000u);
            a0 += __uint_as_float(u3.x << 16); a1 += __uint_as_float(u3.x & 0xffff0000u);
            a2 += __uint_as_float(u3.y << 16); a3 += __uint_as_float(u3.y & 0xffff0000u);
            if (!more) break;
            i0 = j0; i1 = j1; i2 = j2; i3 = j3;
            e = en;
        }
    }
    float di = dinv[node];
    a0 *= di; a1 *= di; a2 *= di; a3 *= di;
    if (BR){
        if (c2 < 12){
            a0 = fmaxf(a0 + bias[4*c2+0], 0.f);
            a1 = fmaxf(a1 + bias[4*c2+1], 0.f);
            a2 = fmaxf(a2 + bias[4*c2+2], 0.f);
            a3 = fmaxf(a3 + bias[4*c2+3], 0.f);
            uint2 w;
            w.x = (uint)f2b(a0) | ((uint)f2b(a1) << 16);
            w.y = (uint)f2b(a2) | ((uint)f2b(a3) << 16);
            *(uint2*)&out[(size_t)node*48 + c2*4] = w;
        }
    } else {
        uint2 w;
        w.x = (uint)f2b(a0) | ((uint)f2b(a1) << 16);
        w.y = (uint)f2b(a2) | ((uint)f2b(a3) << 16);
        *(uint2*)&out[(size_t)node*64 + c2*4] = w;
    }
}

// ---------------- fused conv MLP: ts = (relu(agg1 @ W1 + b1) @ W2) * dinv  (MFMA) ----------------

__global__ __launch_bounds__(256) void k_conv_mlp(
    const u16* __restrict__ A,      // agg1 [N][64] (58 real cols, rest 0)
    const u16* __restrict__ w1t,    // [96][64] bf16 (transposed, k-padded)
    const float* __restrict__ b1,   // [96]
    const u16* __restrict__ w2t,    // [48][96] bf16 (transposed)
    const float* __restrict__ dinv,
    u16* __restrict__ ts)           // [N][64], cols>=48 zeroed here
{
    __shared__ __align__(16) u16 As[64][72];
    __shared__ __align__(16) u16 Bt1[96][72];
    __shared__ __align__(16) u16 Bt2[48][104];
    __shared__ __align__(16) u16 sh1[64][104];
    __shared__ float sb1[96];
    const int tid = threadIdx.x;
    {
        const u16* Ab = A + (size_t)blockIdx.x*64*64;
        for (int i = tid; i < 512; i += 256){
            int r = i >> 3, s = i & 7;
            *(uint4*)&As[r][s*8] = *(const uint4*)&Ab[r*64 + s*8];
        }
    }
    for (int i = tid; i < 768; i += 256){
        int n = i >> 3, s = i & 7;
        *(uint4*)&Bt1[n][s*8] = *(const uint4*)&w1t[n*64 + s*8];
    }
    for (int i = tid; i < 576; i += 256){
        int n = i / 12, s = i % 12;
        *(uint4*)&Bt2[n][s*8] = *(const uint4*)&w2t[n*96 + s*8];
    }
    if (tid < 96) sb1[tid] = b1[tid];
    __syncthreads();

    const int wv = tid >> 6, l = tid & 63;
    const int lr = l & 15, lg = l >> 4;
    const int r0 = wv*16;

    f32x4 acc1[6] = {};
    #pragma unroll
    for (int s = 0; s < 2; ++s){
        s16x8 af = *(const s16x8*)&As[r0+lr][s*32 + lg*8];
        #pragma unroll
        for (int t = 0; t < 6; ++t){
            s16x8 bf = *(const s16x8*)&Bt1[t*16+lr][s*32 + lg*8];
            acc1[t] = __builtin_amdgcn_mfma_f32_16x16x32_bf16(af, bf, acc1[t], 0, 0, 0);
        }
    }
    #pragma unroll
    for (int t = 0; t < 6; ++t){
        int col = t*16 + lr;
        float bias = sb1[col];
        #pragma unroll
        for (int r = 0; r < 4; ++r)
            sh1[r0 + lg*4 + r][col] = f2b(fmaxf(acc1[t][r] + bias, 0.f));
    }
    __syncthreads();

    f32x4 acc2[3] = {};
    #pragma unroll
    for (int s = 0; s < 3; ++s){
        s16x8 af = *(const s16x8*)&sh1[r0+lr][s*32 + lg*8];
        #pragma unroll
        for (int t = 0; t < 3; ++t){
            s16x8 bf = *(const s16x8*)&Bt2[t*16+lr][s*32 + lg*8];
            acc2[t] = __builtin_amdgcn_mfma_f32_16x16x32_bf16(af, bf, acc2[t], 0, 0, 0);
        }
    }
    size_t gbase = (size_t)blockIdx.x*64;
    #pragma unroll
    for (int r = 0; r < 4; ++r){
        size_t row = gbase + r0 + lg*4 + r;
        float dv = dinv[row];
        #pragma unroll
        for (int t = 0; t < 3; ++t)
            ts[row*64 + t*16 + lr] = f2b(acc2[t][r] * dv);
        ts[row*64 + 48 + lr] = 0;
    }
}

// ---------------- fused MLP head: 32 graphs/block, g1 in LDS, l2/l3 fused ----------------

__global__ __launch_bounds__(256) void k_head(
    const u16* __restrict__ A,      // agg2, graph rows [8192][1920] bf16
    const u16* __restrict__ l1wt,   // [256][1920]
    const float* __restrict__ l1b,
    const u16* __restrict__ l2wt,   // [64][256]
    const float* __restrict__ l2b,
    const float* __restrict__ l3w, const float* __restrict__ l3b,
    float* __restrict__ out)
{
    __shared__ __align__(16) u16 As[32][72];
    __shared__ __align__(16) u16 Bt[256][72];
    __shared__ float part[32][2];
    u16 (*sh1)[264] = (u16(*)[264])&Bt[0][0];
    const int tid = threadIdx.x;
    const int g0 = blockIdx.x*32;
    const int w = tid >> 6, l = tid & 63;
    const int lr = l & 15, lg = l >> 4;
    const int r0 = (w & 1)*16;
    const int c0 = (w >> 1)*128;
    f32x4 acc[8] = {};
    for (int k0 = 0; k0 < 1920; k0 += 64){
        __syncthreads();
        {
            int r = tid >> 3, s = tid & 7;
            *(uint4*)&As[r][s*8] = *(const uint4*)&A[(size_t)(g0+r)*1920 + k0 + s*8];
        }
        for (int i = tid; i < 2048; i += 256){
            int n = i >> 3, s = i & 7;
            *(uint4*)&Bt[n][s*8] = *(const uint4*)&l1wt[(size_t)n*1920 + k0 + s*8];
        }
        __syncthreads();
        #pragma unroll
        for (int s = 0; s < 2; ++s){
            s16x8 af = *(const s16x8*)&As[r0+lr][s*32 + lg*8];
            #pragma unroll
            for (int t = 0; t < 8; ++t){
                s16x8 bf = *(const s16x8*)&Bt[c0 + t*16 + lr][s*32 + lg*8];
                acc[t] = __builtin_amdgcn_mfma_f32_16x16x32_bf16(af, bf, acc[t], 0, 0, 0);
            }
        }
    }
    __syncthreads();   // everyone done reading Bt before overlay write
    #pragma unroll
    for (int t = 0; t < 8; ++t){
        int col = c0 + t*16 + lr;
        float bs = l1b[col];
        #pragma unroll
        for (int r = 0; r < 4; ++r)
            sh1[r0 + lg*4 + r][col] = f2b(fmaxf(acc[t][r] + bs, 0.f));
    }
    __syncthreads();
    f32x4 acc2[2] = {};
    #pragma unroll
    for (int s = 0; s < 8; ++s){
        s16x8 af = *(const s16x8*)&sh1[r0+lr][s*32 + lg*8];
        #pragma unroll
        for (int t = 0; t < 2; ++t){
            int col = (w>>1)*32 + t*16 + lr;
            s16x8 bf = *(const s16x8*)&l2wt[(size_t)col*256 + s*32 + lg*8];
            acc2[t] = __builtin_amdgcn_mfma_f32_16x16x32_bf16(af, bf, acc2[t], 0, 0, 0);
        }
    }
    float p[4];
    #pragma unroll
    for (int r = 0; r < 4; ++r){
        p[r] = 0.f;
        #pragma unroll
        for (int t = 0; t < 2; ++t){
            int col = (w>>1)*32 + t*16 + lr;
            p[r] += fmaxf(acc2[t][r] + l2b[col], 0.f) * l3w[col];
        }
    }
    #pragma unroll
    for (int o = 1; o < 16; o <<= 1){
        #pragma unroll
        for (int r = 0; r < 4; ++r) p[r] += __shfl_xor(p[r], o);
    }
    if (lr == 0){
        #pragma unroll
        for (int r = 0; r < 4; ++r)
            part[r0 + lg*4 + r][w>>1] = p[r];
    }
    __syncthreads();
    if (tid < 32)
        out[g0 + tid] = 1.0f / (1.0f + expf(-(part[tid][0] + part[tid][1] + l3b[0])));
}

extern "C" void kernel_launch(void* const* d_in, const int* in_sizes, int n_in,
                              void* d_out, int out_size, void* d_ws, size_t ws_size,
                              hipStream_t stream){
    const float* x   = (const float*)d_in[0];
    const int*   ei  = (const int*)  d_in[1];
    const int*   src = ei;
    const int*   dst = ei + N_EDGES;
    const float* W1  = (const float*)d_in[2];
    const float* b1  = (const float*)d_in[3];
    const float* W2  = (const float*)d_in[4];
    const float* b2  = (const float*)d_in[5];
    const float* l1w = (const float*)d_in[6];
    const float* l1b = (const float*)d_in[7];
    const float* l2w = (const float*)d_in[8];
    const float* l2b = (const float*)d_in[9];
    const float* l3w = (const float*)d_in[10];
    const float* l3b = (const float*)d_in[11];
    float* out = (float*)d_out;

    char* w = (char*)d_ws;
    auto alloc = [&](size_t bytes){ void* p = (void*)w; w += (bytes + 255) & ~(size_t)255; return p; };
    float* dinv   = (float*)alloc((size_t)N_NODES*4);
    int*   rowst  = (int*)  alloc((size_t)N_NODES*4);
    int*   rend   = (int*)  alloc((size_t)N_NODES*4);
    int*   perm   = (int*)  alloc((size_t)N_NODES*4);
    int*   gcur   = (int*)  alloc(NB*4);
    u16*   w1t    = (u16*)  alloc(96*64*2);
    u16*   w2t    = (u16*)  alloc(48*96*2);
    u16*   l1wt   = (u16*)  alloc((size_t)256*1920*2);
    u16*   l2wt   = (u16*)  alloc((size_t)64*256*2);
    int*   csr    = (int*)  alloc((size_t)NB*BCAPE*4);
    char*  BUF_A  = (char*) alloc((size_t)N_NODES*64*2);  // agg1 -> agg2
    char*  BUF_B  = (char*) alloc((size_t)N_NODES*64*2);  // staging -> xs
    char*  BUF_C  = (char*) alloc((size_t)N_NODES*64*2);  // ts

    u16*   agg1    = (u16*)BUF_A;
    u16*   agg2    = (u16*)BUF_A;        // dense 48 per node == graph-major [8192][1920]
    uint2* staging = (uint2*)BUF_B;      // 23.6MB, dead after k_bucket
    uint*  xs32    = (uint*)BUF_B;
    u16*   ts      = (u16*)BUF_C;

    // weight transposes (independent, tiny)
    k_trconv<<<dim3(1,2),  256, 0, stream>>>(W1,  w1t,  58,   96,  64);
    k_trconv<<<dim3(2,1),  256, 0, stream>>>(W2,  w2t,  96,   48,  96);
    k_trconv<<<dim3(30,4), 256, 0, stream>>>(l1w, l1wt, 1920, 256, 1920);
    k_trconv<<<dim3(4,1),  256, 0, stream>>>(l2w, l2wt, 256,  64,  256);

    // bucketed CSR build (fixed-cap buckets, no global histogram/scan)
    k_initgcur <<<3,   256, 0, stream>>>(gcur);
    k_partition<<<640, 256, 0, stream>>>(src, dst, gcur, staging);
    k_bucket   <<<640, 512, 0, stream>>>(staging, gcur, rowst, rend, dinv, csr, perm);

    // conv1
    k_prescale2  <<<40960, 256, 0, stream>>>(x, dinv, xs32);
    k_gatherv<0> <<<20480, 256, 0, stream>>>(rowst, rend, csr, dinv, perm,
                                             (const uint2*)xs32, nullptr, agg1);
    k_conv_mlp   <<<5120,  256, 0, stream>>>(agg1, w1t, b1, w2t, dinv, ts);

    // conv2
    k_gatherv<1> <<<20480, 256, 0, stream>>>(rowst, rend, csr, dinv, perm,
                                             (const uint2*)ts, b2, agg2);

    // fused MLP head
    k_head       <<<256,   256, 0, stream>>>(agg2, l1wt, l1b, l2wt, l2b, l3w, l3b, out);
}

// Round 7
// 341.277 us; speedup vs baseline: 6.8007x; 1.0649x over previous
//
#include <hip/hip_runtime.h>

#define N_NODES 327680
#define N_EDGES 2621440
#define NGRAPH  8192
#define NB      640          // dst buckets (512 nodes each)
#define BCAPE   4608         // fixed per-bucket capacity (mean 4096, +8 sigma)

typedef unsigned int uint;
typedef unsigned short u16;
typedef __attribute__((ext_vector_type(8))) short s16x8;
typedef __attribute__((ext_vector_type(4))) float f32x4;

__device__ __forceinline__ float bl(uint u){ return __uint_as_float(u << 16); }
__device__ __forceinline__ float bh(uint u){ return __uint_as_float(u & 0xffff0000u); }
__device__ __forceinline__ u16 f2b(float f){
    uint u = __float_as_uint(f);
    u += 0x7fffu + ((u>>16)&1u);          // round-to-nearest-even
    return (u16)(u>>16);
}
__device__ __forceinline__ uint pk(float a, float b){
    return (uint)f2b(a) | ((uint)f2b(b) << 16);
}

// ---------------- prep: weight transposes (bf16) + gcur zero, one launch ----------------

__device__ void tr_tile(const float* __restrict__ in, u16* __restrict__ out,
                        int K, int N, int Kpad, int kb, int nb){
    __shared__ u16 t[64][72];
    for (int i = threadIdx.x; i < 4096; i += 256){
        int k = i >> 6, n = i & 63;
        int gk = kb + k, gn = nb + n;
        float v = (gk < K && gn < N) ? in[(size_t)gk*N + gn] : 0.f;
        t[n][k] = f2b(v);
    }
    __syncthreads();
    for (int i = threadIdx.x; i < 4096; i += 256){
        int n = i >> 6, k = i & 63;
        int gk = kb + k, gn = nb + n;
        if (gn < N && gk < Kpad) out[(size_t)gn*Kpad + gk] = t[n][k];
    }
}

__global__ __launch_bounds__(256) void k_prep(
    const float* __restrict__ W1, const float* __restrict__ W2,
    const float* __restrict__ l1w, const float* __restrict__ l2w,
    u16* __restrict__ w1t, u16* __restrict__ w2t,
    u16* __restrict__ l1wt, u16* __restrict__ l2wt, int* __restrict__ gcur)
{
    int b = blockIdx.x;
    if (b < 120)      tr_tile(l1w, l1wt, 1920, 256, 1920, (b%30)*64, (b/30)*64);
    else if (b < 124) tr_tile(l2w, l2wt, 256,  64,  256,  (b-120)*64, 0);
    else if (b < 126) tr_tile(W1,  w1t,  58,   96,  64,   0, (b-124)*64);
    else if (b < 128) tr_tile(W2,  w2t,  96,   48,  96,   (b-126)*64, 0);
    else {
        for (int i = threadIdx.x; i < NB; i += 256) gcur[i] = 0;
    }
}

// ---------------- partition edges into fixed-cap dst-buckets (packed uint) ----------------

__global__ __launch_bounds__(256) void k_partition(
    const int* __restrict__ src, const int* __restrict__ dst,
    int* __restrict__ gcur, uint* __restrict__ staging)
{
    __shared__ int cnt[NB], base_[NB];
    int tid = threadIdx.x;
    for (int i = tid; i < NB; i += 256) cnt[i] = 0;
    __syncthreads();
    int e0 = blockIdx.x*4096;
    int d[16];
    #pragma unroll
    for (int j = 0; j < 16; ++j){
        d[j] = dst[e0 + j*256 + tid];
        atomicAdd(&cnt[d[j] >> 9], 1);
    }
    __syncthreads();
    for (int i = tid; i < NB; i += 256)
        base_[i] = atomicAdd(&gcur[i], cnt[i]);
    __syncthreads();
    for (int i = tid; i < NB; i += 256) cnt[i] = 0;
    __syncthreads();
    #pragma unroll
    for (int j = 0; j < 16; ++j){
        int e = e0 + j*256 + tid;
        int b = d[j] >> 9;
        int r = atomicAdd(&cnt[b], 1);
        staging[(uint)b*BCAPE + base_[b] + r] = (uint)src[e] | ((uint)(d[j] & 511) << 19);
    }
}

// ---- per-bucket: degree, dinv, row starts, csr place, degree-sorted perm (LDS-local) ----

__global__ __launch_bounds__(512) void k_bucket(
    const uint* __restrict__ staging, const int* __restrict__ gcur,
    int* __restrict__ rowst, int* __restrict__ rendg, float* __restrict__ dinvg,
    int* __restrict__ csr, int* __restrict__ perm)
{
    __shared__ uint sedge[BCAPE];
    __shared__ int deg[512];
    __shared__ int sc[512];
    __shared__ int cur[512];
    __shared__ int dh[64], dbase[64];
    const int b = blockIdx.x;
    const int tid = threadIdx.x;
    const int lo = b*BCAPE;
    int cnt = gcur[b];
    if (cnt > BCAPE) cnt = BCAPE;   // safety (8-sigma margin, never expected)
    deg[tid] = 0;
    if (tid < 64) dh[tid] = 0;
    __syncthreads();
    for (int t = tid; t < cnt; t += 512){
        uint ed = staging[lo + t];
        sedge[t] = ed;
        atomicAdd(&deg[ed >> 19], 1);
    }
    __syncthreads();
    int d = deg[tid];
    sc[tid] = d;
    __syncthreads();
    for (int o = 1; o < 512; o <<= 1){
        int v = (tid >= o) ? sc[tid-o] : 0;
        __syncthreads();
        sc[tid] += v;
        __syncthreads();
    }
    int incl = sc[tid];
    int excl = incl - d;
    int gnode = b*512 + tid;
    rowst[gnode] = lo + excl;
    rendg[gnode] = lo + incl;
    dinvg[gnode] = 1.0f / sqrtf((float)(d + 1));
    cur[tid] = lo + excl;
    int bin = min(d, 63);
    atomicAdd(&dh[bin], 1);
    __syncthreads();
    if (tid == 0){
        int a = 0;
        #pragma unroll
        for (int i = 0; i < 64; ++i){ dbase[i] = a; a += dh[i]; dh[i] = 0; }
    }
    __syncthreads();
    int pos = dbase[bin] + atomicAdd(&dh[bin], 1);
    perm[b*512 + pos] = gnode;
    for (int t = tid; t < cnt; t += 512){
        uint ed = sedge[t];
        int p = atomicAdd(&cur[ed >> 19], 1);
        csr[p] = (int)(ed & 0x7FFFFu);
    }
}

// ---------------- prescale x*dinv -> packed bf16x2, padded to 64 cols ----------------

__global__ void k_prescale2(const float* __restrict__ x, const float* __restrict__ dinv,
                            uint* __restrict__ xs32){
    int gid = blockIdx.x*256 + threadIdx.x;
    int node = gid >> 5, c = gid & 31;
    float dv = dinv[node];
    float a = 0.f, b = 0.f;
    if (c < 29){
        float2 v = *(const float2*)&x[(size_t)node*58 + 2*c];
        a = v.x * dv; b = v.y * dv;
    }
    xs32[(size_t)node*32 + c] = pk(a, b);
}

// ---- CSR gather: 8 lanes/node x uint4 (16B), 8 edges batched, degree-sorted perm ----

template<int BR>
__global__ __launch_bounds__(256) void k_gatherv(
    const int* __restrict__ rs, const int* __restrict__ re,
    const int* __restrict__ csr, const float* __restrict__ dinv,
    const int* __restrict__ perm,
    const uint4* __restrict__ feat4,   // [N][8] rows of 128B packed bf16
    const float* __restrict__ bias,
    u16* __restrict__ out)
{
    int slot = (blockIdx.x*256 + threadIdx.x) >> 3;
    int c4 = threadIdx.x & 7;
    int node = perm[slot];
    uint4 u = feat4[((uint)node << 3) + c4];
    float a0 = bl(u.x), a1 = bh(u.x), a2 = bl(u.y), a3 = bh(u.y);
    float a4 = bl(u.z), a5 = bh(u.z), a6 = bl(u.w), a7 = bh(u.w);
    int e = rs[node];
    const int e1 = re[node];
    while (e < e1){
        const int last = e1 - 1;
        int idx[8];
        #pragma unroll
        for (int k = 0; k < 8; ++k) idx[k] = csr[min(e + k, last)];
        uint4 uu[8];
        #pragma unroll
        for (int k = 0; k < 8; ++k) uu[k] = feat4[((uint)idx[k] << 3) + c4];
        #pragma unroll
        for (int k = 0; k < 8; ++k){
            if (e + k < e1){
                a0 += bl(uu[k].x); a1 += bh(uu[k].x);
                a2 += bl(uu[k].y); a3 += bh(uu[k].y);
                a4 += bl(uu[k].z); a5 += bh(uu[k].z);
                a6 += bl(uu[k].w); a7 += bh(uu[k].w);
            }
        }
        e += 8;
    }
    float di = dinv[node];
    a0 *= di; a1 *= di; a2 *= di; a3 *= di;
    a4 *= di; a5 *= di; a6 *= di; a7 *= di;
    if (BR){
        if (c4 < 6){
            float4 bz0 = *(const float4*)&bias[8*c4];
            float4 bz1 = *(const float4*)&bias[8*c4 + 4];
            a0 = fmaxf(a0 + bz0.x, 0.f); a1 = fmaxf(a1 + bz0.y, 0.f);
            a2 = fmaxf(a2 + bz0.z, 0.f); a3 = fmaxf(a3 + bz0.w, 0.f);
            a4 = fmaxf(a4 + bz1.x, 0.f); a5 = fmaxf(a5 + bz1.y, 0.f);
            a6 = fmaxf(a6 + bz1.z, 0.f); a7 = fmaxf(a7 + bz1.w, 0.f);
            uint4 w;
            w.x = pk(a0,a1); w.y = pk(a2,a3); w.z = pk(a4,a5); w.w = pk(a6,a7);
            *(uint4*)&out[(size_t)node*48 + c4*8] = w;
        }
    } else {
        uint4 w;
        w.x = pk(a0,a1); w.y = pk(a2,a3); w.z = pk(a4,a5); w.w = pk(a6,a7);
        *(uint4*)&out[(size_t)node*64 + c4*8] = w;
    }
}

// ---------------- fused conv MLP: ts = (relu(agg1 @ W1 + b1) @ W2) * dinv  (MFMA) ----------------

__global__ __launch_bounds__(256) void k_conv_mlp(
    const u16* __restrict__ A,      // agg1 [N][64] (58 real cols, rest 0)
    const u16* __restrict__ w1t,    // [96][64] bf16 (transposed, k-padded)
    const float* __restrict__ b1,   // [96]
    const u16* __restrict__ w2t,    // [48][96] bf16 (transposed)
    const float* __restrict__ dinv,
    u16* __restrict__ ts)           // [N][64], cols>=48 zeroed here
{
    __shared__ __align__(16) u16 As[64][72];
    __shared__ __align__(16) u16 Bt1[96][72];
    __shared__ __align__(16) u16 Bt2[48][104];
    __shared__ __align__(16) u16 sh1[64][104];
    __shared__ float sb1[96];
    const int tid = threadIdx.x;
    {
        const u16* Ab = A + (size_t)blockIdx.x*64*64;
        for (int i = tid; i < 512; i += 256){
            int r = i >> 3, s = i & 7;
            *(uint4*)&As[r][s*8] = *(const uint4*)&Ab[r*64 + s*8];
        }
    }
    for (int i = tid; i < 768; i += 256){
        int n = i >> 3, s = i & 7;
        *(uint4*)&Bt1[n][s*8] = *(const uint4*)&w1t[n*64 + s*8];
    }
    for (int i = tid; i < 576; i += 256){
        int n = i / 12, s = i % 12;
        *(uint4*)&Bt2[n][s*8] = *(const uint4*)&w2t[n*96 + s*8];
    }
    if (tid < 96) sb1[tid] = b1[tid];
    __syncthreads();

    const int wv = tid >> 6, l = tid & 63;
    const int lr = l & 15, lg = l >> 4;
    const int r0 = wv*16;

    f32x4 acc1[6] = {};
    #pragma unroll
    for (int s = 0; s < 2; ++s){
        s16x8 af = *(const s16x8*)&As[r0+lr][s*32 + lg*8];
        #pragma unroll
        for (int t = 0; t < 6; ++t){
            s16x8 bf = *(const s16x8*)&Bt1[t*16+lr][s*32 + lg*8];
            acc1[t] = __builtin_amdgcn_mfma_f32_16x16x32_bf16(af, bf, acc1[t], 0, 0, 0);
        }
    }
    #pragma unroll
    for (int t = 0; t < 6; ++t){
        int col = t*16 + lr;
        float bias = sb1[col];
        #pragma unroll
        for (int r = 0; r < 4; ++r)
            sh1[r0 + lg*4 + r][col] = f2b(fmaxf(acc1[t][r] + bias, 0.f));
    }
    __syncthreads();

    f32x4 acc2[3] = {};
    #pragma unroll
    for (int s = 0; s < 3; ++s){
        s16x8 af = *(const s16x8*)&sh1[r0+lr][s*32 + lg*8];
        #pragma unroll
        for (int t = 0; t < 3; ++t){
            s16x8 bf = *(const s16x8*)&Bt2[t*16+lr][s*32 + lg*8];
            acc2[t] = __builtin_amdgcn_mfma_f32_16x16x32_bf16(af, bf, acc2[t], 0, 0, 0);
        }
    }
    size_t gbase = (size_t)blockIdx.x*64;
    #pragma unroll
    for (int r = 0; r < 4; ++r){
        size_t row = gbase + r0 + lg*4 + r;
        float dv = dinv[row];
        #pragma unroll
        for (int t = 0; t < 3; ++t)
            ts[row*64 + t*16 + lr] = f2b(acc2[t][r] * dv);
        ts[row*64 + 48 + lr] = 0;
    }
}

// ---------------- fused MLP head: 32 graphs/block, g1 in LDS, l2/l3 fused ----------------

__global__ __launch_bounds__(256) void k_head(
    const u16* __restrict__ A,      // agg2, graph rows [8192][1920] bf16
    const u16* __restrict__ l1wt,   // [256][1920]
    const float* __restrict__ l1b,
    const u16* __restrict__ l2wt,   // [64][256]
    const float* __restrict__ l2b,
    const float* __restrict__ l3w, const float* __restrict__ l3b,
    float* __restrict__ out)
{
    __shared__ __align__(16) u16 As[32][72];
    __shared__ __align__(16) u16 Bt[256][72];
    __shared__ float part[32][2];
    u16 (*sh1)[264] = (u16(*)[264])&Bt[0][0];
    const int tid = threadIdx.x;
    const int g0 = blockIdx.x*32;
    const int w = tid >> 6, l = tid & 63;
    const int lr = l & 15, lg = l >> 4;
    const int r0 = (w & 1)*16;
    const int c0 = (w >> 1)*128;
    f32x4 acc[8] = {};
    for (int k0 = 0; k0 < 1920; k0 += 64){
        __syncthreads();
        {
            int r = tid >> 3, s = tid & 7;
            *(uint4*)&As[r][s*8] = *(const uint4*)&A[(size_t)(g0+r)*1920 + k0 + s*8];
        }
        for (int i = tid; i < 2048; i += 256){
            int n = i >> 3, s = i & 7;
            *(uint4*)&Bt[n][s*8] = *(const uint4*)&l1wt[(size_t)n*1920 + k0 + s*8];
        }
        __syncthreads();
        #pragma unroll
        for (int s = 0; s < 2; ++s){
            s16x8 af = *(const s16x8*)&As[r0+lr][s*32 + lg*8];
            #pragma unroll
            for (int t = 0; t < 8; ++t){
                s16x8 bf = *(const s16x8*)&Bt[c0 + t*16 + lr][s*32 + lg*8];
                acc[t] = __builtin_amdgcn_mfma_f32_16x16x32_bf16(af, bf, acc[t], 0, 0, 0);
            }
        }
    }
    __syncthreads();   // everyone done reading Bt before overlay write
    #pragma unroll
    for (int t = 0; t < 8; ++t){
        int col = c0 + t*16 + lr;
        float bs = l1b[col];
        #pragma unroll
        for (int r = 0; r < 4; ++r)
            sh1[r0 + lg*4 + r][col] = f2b(fmaxf(acc[t][r] + bs, 0.f));
    }
    __syncthreads();
    f32x4 acc2[2] = {};
    #pragma unroll
    for (int s = 0; s < 8; ++s){
        s16x8 af = *(const s16x8*)&sh1[r0+lr][s*32 + lg*8];
        #pragma unroll
        for (int t = 0; t < 2; ++t){
            int col = (w>>1)*32 + t*16 + lr;
            s16x8 bf = *(const s16x8*)&l2wt[(size_t)col*256 + s*32 + lg*8];
            acc2[t] = __builtin_amdgcn_mfma_f32_16x16x32_bf16(af, bf, acc2[t], 0, 0, 0);
        }
    }
    float p[4];
    #pragma unroll
    for (int r = 0; r < 4; ++r){
        p[r] = 0.f;
        #pragma unroll
        for (int t = 0; t < 2; ++t){
            int col = (w>>1)*32 + t*16 + lr;
            p[r] += fmaxf(acc2[t][r] + l2b[col], 0.f) * l3w[col];
        }
    }
    #pragma unroll
    for (int o = 1; o < 16; o <<= 1){
        #pragma unroll
        for (int r = 0; r < 4; ++r) p[r] += __shfl_xor(p[r], o);
    }
    if (lr == 0){
        #pragma unroll
        for (int r = 0; r < 4; ++r)
            part[r0 + lg*4 + r][w>>1] = p[r];
    }
    __syncthreads();
    if (tid < 32)
        out[g0 + tid] = 1.0f / (1.0f + expf(-(part[tid][0] + part[tid][1] + l3b[0])));
}

extern "C" void kernel_launch(void* const* d_in, const int* in_sizes, int n_in,
                              void* d_out, int out_size, void* d_ws, size_t ws_size,
                              hipStream_t stream){
    const float* x   = (const float*)d_in[0];
    const int*   ei  = (const int*)  d_in[1];
    const int*   src = ei;
    const int*   dst = ei + N_EDGES;
    const float* W1  = (const float*)d_in[2];
    const float* b1  = (const float*)d_in[3];
    const float* W2  = (const float*)d_in[4];
    const float* b2  = (const float*)d_in[5];
    const float* l1w = (const float*)d_in[6];
    const float* l1b = (const float*)d_in[7];
    const float* l2w = (const float*)d_in[8];
    const float* l2b = (const float*)d_in[9];
    const float* l3w = (const float*)d_in[10];
    const float* l3b = (const float*)d_in[11];
    float* out = (float*)d_out;

    char* w = (char*)d_ws;
    auto alloc = [&](size_t bytes){ void* p = (void*)w; w += (bytes + 255) & ~(size_t)255; return p; };
    float* dinv   = (float*)alloc((size_t)N_NODES*4);
    int*   rowst  = (int*)  alloc((size_t)N_NODES*4);
    int*   rend   = (int*)  alloc((size_t)N_NODES*4);
    int*   perm   = (int*)  alloc((size_t)N_NODES*4);
    int*   gcur   = (int*)  alloc(NB*4);
    u16*   w1t    = (u16*)  alloc(96*64*2);
    u16*   w2t    = (u16*)  alloc(48*96*2);
    u16*   l1wt   = (u16*)  alloc((size_t)256*1920*2);
    u16*   l2wt   = (u16*)  alloc((size_t)64*256*2);
    int*   csr    = (int*)  alloc((size_t)NB*BCAPE*4);
    char*  BUF_A  = (char*) alloc((size_t)N_NODES*64*2);  // agg1 -> agg2
    char*  BUF_B  = (char*) alloc((size_t)N_NODES*64*2);  // staging -> xs
    char*  BUF_C  = (char*) alloc((size_t)N_NODES*64*2);  // ts

    u16*   agg1    = (u16*)BUF_A;
    u16*   agg2    = (u16*)BUF_A;        // dense 48 per node == graph-major [8192][1920]
    uint*  staging = (uint*)BUF_B;       // 11.8MB packed, dead after k_bucket
    uint*  xs32    = (uint*)BUF_B;
    u16*   ts      = (u16*)BUF_C;

    // prep: weight transposes + gcur zero (one launch)
    k_prep     <<<129, 256, 0, stream>>>(W1, W2, l1w, l2w, w1t, w2t, l1wt, l2wt, gcur);

    // bucketed CSR build (fixed-cap buckets)
    k_partition<<<640, 256, 0, stream>>>(src, dst, gcur, staging);
    k_bucket   <<<640, 512, 0, stream>>>(staging, gcur, rowst, rend, dinv, csr, perm);

    // conv1
    k_prescale2  <<<40960, 256, 0, stream>>>(x, dinv, xs32);
    k_gatherv<0> <<<10240, 256, 0, stream>>>(rowst, rend, csr, dinv, perm,
                                             (const uint4*)xs32, nullptr, agg1);
    k_conv_mlp   <<<5120,  256, 0, stream>>>(agg1, w1t, b1, w2t, dinv, ts);

    // conv2
    k_gatherv<1> <<<10240, 256, 0, stream>>>(rowst, rend, csr, dinv, perm,
                                             (const uint4*)ts, b2, agg2);

    // fused MLP head
    k_head       <<<256,   256, 0, stream>>>(agg2, l1wt, l1b, l2wt, l2b, l3w, l3b, out);
}